// Round 1
// baseline (460.345 us; speedup 1.0000x reference)
//
#include <hip/hip_runtime.h>
#include <math.h>

// Bottleneck_49039936586369: deformable attention (DAT-style), fp32 baseline.
// B=8, C=256, H=W=32, heads=8 (HC=32), groups=4 (GC=64), n=1024.
// Pipeline: q=Wq@x -> offset branch (dwconv3x3+LN+GELU+pw+tanh) -> bilinear
// grid-sample -> k/v proj -> flash-style attention (+lepe dwconv residual) -> Wo.

#define NPOS 1024   // H*W
#define CCH  256

// ---------------------------------------------------------------------------
// GEMM: Y[b] = W(256x256) @ X[b](256x1024) + bias.   grid(16,4,8), block 256.
// ---------------------------------------------------------------------------
__global__ __launch_bounds__(256) void gemm256(
    const float* __restrict__ W, const float* __restrict__ bias,
    const float* __restrict__ X, float* __restrict__ Y)
{
    __shared__ float Ws[16][65];                 // [k][m], padded
    __shared__ __align__(16) float Xs[16][64];   // [k][n]
    const int tid = threadIdx.x;
    const int n0 = blockIdx.x * 64;
    const int m0 = blockIdx.y * 64;
    const long b = blockIdx.z;
    const float* Xb = X + b * (long)CCH * NPOS;
    float* Yb = Y + b * (long)CCH * NPOS;
    const int tx = tid & 15, ty = tid >> 4;
    float acc[4][4] = {};
    for (int k0 = 0; k0 < 256; k0 += 16) {
        {
            int m = tid >> 2, k4 = (tid & 3) * 4;
            const float4 w4 = *reinterpret_cast<const float4*>(&W[(m0 + m) * 256 + k0 + k4]);
            Ws[k4 + 0][m] = w4.x; Ws[k4 + 1][m] = w4.y;
            Ws[k4 + 2][m] = w4.z; Ws[k4 + 3][m] = w4.w;
            int kk = tid >> 4, n4 = (tid & 15) * 4;
            *reinterpret_cast<float4*>(&Xs[kk][n4]) =
                *reinterpret_cast<const float4*>(&Xb[(long)(k0 + kk) * NPOS + n0 + n4]);
        }
        __syncthreads();
        #pragma unroll
        for (int kk = 0; kk < 16; ++kk) {
            float a[4], c[4];
            #pragma unroll
            for (int i = 0; i < 4; ++i) a[i] = Ws[kk][ty * 4 + i];
            #pragma unroll
            for (int j = 0; j < 4; ++j) c[j] = Xs[kk][tx * 4 + j];
            #pragma unroll
            for (int i = 0; i < 4; ++i)
                #pragma unroll
                for (int j = 0; j < 4; ++j) acc[i][j] += a[i] * c[j];
        }
        __syncthreads();
    }
    #pragma unroll
    for (int i = 0; i < 4; ++i) {
        float bb = bias[m0 + ty * 4 + i];
        float4 o;
        o.x = acc[i][0] + bb; o.y = acc[i][1] + bb;
        o.z = acc[i][2] + bb; o.w = acc[i][3] + bb;
        *reinterpret_cast<float4*>(&Yb[(long)(m0 + ty * 4 + i) * NPOS + n0 + tx * 4]) = o;
    }
}

// ---------------------------------------------------------------------------
// depthwise 3x3 helper (cross-correlation, zero pad, 32x32 image)
// ---------------------------------------------------------------------------
__device__ __forceinline__ float conv3(const float* __restrict__ img,
                                       const float* __restrict__ w, int y, int x)
{
    float acc = 0.f;
    #pragma unroll
    for (int dy = 0; dy < 3; ++dy) {
        int yy = y + dy - 1;
        if (yy < 0 || yy > 31) continue;
        #pragma unroll
        for (int dx = 0; dx < 3; ++dx) {
            int xx = x + dx - 1;
            if (xx < 0 || xx > 31) continue;
            acc += w[dy * 3 + dx] * img[yy * 32 + xx];
        }
    }
    return acc;
}

// ---------------------------------------------------------------------------
// Offset branch: per (bg,pixel): dwconv3x3(64ch) -> LN(ch) -> GELU(exact) ->
// pw(2x64) -> tanh*4/31 -> +reference grid -> pos (32,1024,2).  32768 threads.
// Two-pass (recompute conv) to avoid per-thread 64-element storage.
// ---------------------------------------------------------------------------
__global__ void offset_kernel(const float* __restrict__ q,
    const float* __restrict__ dww, const float* __restrict__ dwb,
    const float* __restrict__ lng, const float* __restrict__ lnb,
    const float* __restrict__ pww, float* __restrict__ pos)
{
    int gid = blockIdx.x * 256 + threadIdx.x;     // 32*1024
    int p = gid & 1023, bg = gid >> 10;
    int yy = p >> 5, xx = p & 31;
    const float* qb = q + (long)bg * 64 * NPOS;   // channel base bg*64 == b*256+g*64
    float s = 0.f, s2 = 0.f;
    for (int c = 0; c < 64; ++c) {
        float oc = conv3(qb + (long)c * NPOS, dww + c * 9, yy, xx) + dwb[c];
        s += oc; s2 += oc * oc;
    }
    float mu = s * 0.015625f;
    float var = s2 * 0.015625f - mu * mu;
    float rstd = rsqrtf(var + 1e-5f);
    float a0 = 0.f, a1 = 0.f;
    for (int c = 0; c < 64; ++c) {
        float oc = conv3(qb + (long)c * NPOS, dww + c * 9, yy, xx) + dwb[c];
        float on = (oc - mu) * rstd * lng[c] + lnb[c];
        float ge = 0.5f * on * (1.f + erff(on * 0.70710678118654752f));
        a0 += pww[c] * ge;
        a1 += pww[64 + c] * ge;
    }
    const float rng = 4.f / 31.f;   // offset_range * OFFSET_RANGE_FACTOR
    float offy = tanhf(a0) * rng;
    float offx = tanhf(a1) * rng;
    float ry = ((yy + 0.5f) / 31.f) * 2.f - 1.f;
    float rx = ((xx + 0.5f) / 31.f) * 2.f - 1.f;
    pos[(long)bg * 2048 + p * 2 + 0] = offy + ry;
    pos[(long)bg * 2048 + p * 2 + 1] = offx + rx;
}

// ---------------------------------------------------------------------------
// Bilinear grid-sample (align_corners=True, zero padding).  2M threads.
// xs layout (B,256,1024) == (bg*64+cc, p).
// ---------------------------------------------------------------------------
__global__ void sample_kernel(const float* __restrict__ x,
    const float* __restrict__ pos, float* __restrict__ xs)
{
    int gid = blockIdx.x * 256 + threadIdx.x;     // 2^21
    int p = gid & 1023;
    int cc = (gid >> 10) & 63;
    int bg = gid >> 16;
    float py = pos[(long)bg * 2048 + p * 2 + 0];
    float px = pos[(long)bg * 2048 + p * 2 + 1];
    float fy = (py + 1.f) * 15.5f;                // 0.5*(Hi-1)
    float fx = (px + 1.f) * 15.5f;
    float y0f = floorf(fy), x0f = floorf(fx);
    int y0 = (int)y0f, x0 = (int)x0f;
    float yw = fy - y0f, xw = fx - x0f;
    const float* img = x + ((long)bg * 64 + cc) * NPOS;
    float acc = 0.f;
    {
        int yi = y0, xi = x0;     float w = (1.f - yw) * (1.f - xw);
        if (yi >= 0 && yi < 32 && xi >= 0 && xi < 32) acc += w * img[yi * 32 + xi];
    }
    {
        int yi = y0, xi = x0 + 1; float w = (1.f - yw) * xw;
        if (yi >= 0 && yi < 32 && xi >= 0 && xi < 32) acc += w * img[yi * 32 + xi];
    }
    {
        int yi = y0 + 1, xi = x0; float w = yw * (1.f - xw);
        if (yi >= 0 && yi < 32 && xi >= 0 && xi < 32) acc += w * img[yi * 32 + xi];
    }
    {
        int yi = y0 + 1, xi = x0 + 1; float w = yw * xw;
        if (yi >= 0 && yi < 32 && xi >= 0 && xi < 32) acc += w * img[yi * 32 + xi];
    }
    xs[((long)bg * 64 + cc) * NPOS + p] = acc;
}

// ---------------------------------------------------------------------------
// lepe = dwconv3x3(q, rpe weights) + bias.  2M threads, layout (b,c,p)=gid.
// ---------------------------------------------------------------------------
__global__ void lepe_kernel(const float* __restrict__ q,
    const float* __restrict__ w, const float* __restrict__ b,
    float* __restrict__ lepe)
{
    int gid = blockIdx.x * 256 + threadIdx.x;     // 2^21
    int p = gid & 1023;
    int c = (gid >> 10) & 255;
    int yy = p >> 5, xx = p & 31;
    const float* img = q + (long)(gid - p);       // (bb*256+c)*1024
    lepe[gid] = conv3(img, w + c * 9, yy, xx) + b[c];
}

// ---------------------------------------------------------------------------
// Fused attention, flash-style online softmax.
// grid(16 mtiles, 64 bh), block 256.  Per block: 64 queries, loop 16 n-tiles
// of 64 keys.  Thread (g=tid&15, mq=tid>>4): 4 m x 4 n scores; PV via LDS P
// tile; each g owns output channels {2g, 2g+1}.
// ---------------------------------------------------------------------------
__global__ __launch_bounds__(256) void attn_kernel(
    const float* __restrict__ q, const float* __restrict__ k,
    const float* __restrict__ v, const float* __restrict__ lepe,
    float* __restrict__ out)
{
    __shared__ float qT[64][33];
    __shared__ float kT[64][33];
    __shared__ float vT[64][33];
    __shared__ float pT[64][65];
    const int tid = threadIdx.x;
    const int mt = blockIdx.x;          // 0..15
    const int bh = blockIdx.y;          // 0..63
    const long chbase = (long)bh * 32 * NPOS;
    const float scale = 0.17677669529663687f;   // 32^-0.5 (folded into q)
    const int m0 = mt * 64;
    #pragma unroll
    for (int i = 0; i < 8; ++i) {
        int idx = tid + i * 256;
        int m = idx & 63, c = idx >> 6;
        qT[m][c] = q[chbase + (long)c * NPOS + m0 + m] * scale;
    }
    const int g = tid & 15, mq = tid >> 4;
    float accv[4][2] = {};
    float Mr[4], Lr[4];
    #pragma unroll
    for (int i = 0; i < 4; ++i) { Mr[i] = -1e30f; Lr[i] = 0.f; }

    for (int nt = 0; nt < 16; ++nt) {
        const int n0 = nt * 64;
        __syncthreads();   // protect kT/vT/pT from previous iteration
        #pragma unroll
        for (int i = 0; i < 8; ++i) {
            int idx = tid + i * 256;
            int n = idx & 63, c = idx >> 6;
            kT[n][c] = k[chbase + (long)c * NPOS + n0 + n];
            vT[n][c] = v[chbase + (long)c * NPOS + n0 + n];
        }
        __syncthreads();
        float S[4][4] = {};
        #pragma unroll
        for (int c = 0; c < 32; ++c) {
            float qv[4], kv[4];
            #pragma unroll
            for (int mm = 0; mm < 4; ++mm) qv[mm] = qT[mq * 4 + mm][c];
            #pragma unroll
            for (int nn = 0; nn < 4; ++nn) kv[nn] = kT[g * 4 + nn][c];
            #pragma unroll
            for (int mm = 0; mm < 4; ++mm)
                #pragma unroll
                for (int nn = 0; nn < 4; ++nn) S[mm][nn] += qv[mm] * kv[nn];
        }
        #pragma unroll
        for (int mm = 0; mm < 4; ++mm) {
            float mx = fmaxf(fmaxf(S[mm][0], S[mm][1]), fmaxf(S[mm][2], S[mm][3]));
            #pragma unroll
            for (int off = 1; off < 16; off <<= 1) mx = fmaxf(mx, __shfl_xor(mx, off));
            float Mn  = fmaxf(Mr[mm], mx);
            float esc = __expf(Mr[mm] - Mn);
            Mr[mm] = Mn;
            float rs = 0.f;
            #pragma unroll
            for (int nn = 0; nn < 4; ++nn) { S[mm][nn] = __expf(S[mm][nn] - Mn); rs += S[mm][nn]; }
            #pragma unroll
            for (int off = 1; off < 16; off <<= 1) rs += __shfl_xor(rs, off);
            Lr[mm] = Lr[mm] * esc + rs;
            accv[mm][0] *= esc; accv[mm][1] *= esc;
            pT[mq * 4 + mm][g * 4 + 0] = S[mm][0];
            pT[mq * 4 + mm][g * 4 + 1] = S[mm][1];
            pT[mq * 4 + mm][g * 4 + 2] = S[mm][2];
            pT[mq * 4 + mm][g * 4 + 3] = S[mm][3];
        }
        __syncthreads();
        #pragma unroll 8
        for (int n = 0; n < 64; ++n) {
            float v0 = vT[n][2 * g], v1 = vT[n][2 * g + 1];
            #pragma unroll
            for (int mm = 0; mm < 4; ++mm) {
                float pr = pT[mq * 4 + mm][n];
                accv[mm][0] += pr * v0;
                accv[mm][1] += pr * v1;
            }
        }
    }
    __syncthreads();
    // stage output tile (reuse qT memory: 32*65 = 2080 <= 64*33 = 2112 floats)
    float* oT = &qT[0][0];
    #pragma unroll
    for (int mm = 0; mm < 4; ++mm) {
        float inv = 1.f / Lr[mm];
        oT[(2 * g + 0) * 65 + mq * 4 + mm] = accv[mm][0] * inv;
        oT[(2 * g + 1) * 65 + mq * 4 + mm] = accv[mm][1] * inv;
    }
    __syncthreads();
    #pragma unroll
    for (int i = 0; i < 8; ++i) {
        int idx = tid + i * 256;
        int m = idx & 63, c = idx >> 6;
        long gi = chbase + (long)c * NPOS + m0 + m;
        out[gi] = oT[c * 65 + m] + lepe[gi];
    }
}

// ---------------------------------------------------------------------------
extern "C" void kernel_launch(void* const* d_in, const int* in_sizes, int n_in,
                              void* d_out, int out_size, void* d_ws, size_t ws_size,
                              hipStream_t stream)
{
    const float* x   = (const float*)d_in[0];
    const float* Wq  = (const float*)d_in[1];
    const float* bq  = (const float*)d_in[2];
    const float* Wk  = (const float*)d_in[3];
    const float* bk  = (const float*)d_in[4];
    const float* Wv  = (const float*)d_in[5];
    const float* bv  = (const float*)d_in[6];
    const float* Wo  = (const float*)d_in[7];
    const float* bo  = (const float*)d_in[8];
    const float* odw = (const float*)d_in[9];
    const float* odb = (const float*)d_in[10];
    const float* olg = (const float*)d_in[11];
    const float* olb = (const float*)d_in[12];
    const float* opw = (const float*)d_in[13];
    const float* rdw = (const float*)d_in[14];
    const float* rdb = (const float*)d_in[15];

    float* ws = (float*)d_ws;
    const size_t SZ = (size_t)8 * 256 * 1024;   // 2M floats per (B,C,n) buffer
    float* qb   = ws;            // q projection
    float* xs   = ws + SZ;       // x_sampled; later reused as attention output
    float* kb   = ws + 2 * SZ;
    float* vb   = ws + 3 * SZ;
    float* lep  = ws + 4 * SZ;
    float* pos  = ws + 5 * SZ;   // 32*1024*2 floats
    float* aout = xs;            // alias: xs is dead after k/v projections
    float* y    = (float*)d_out;

    dim3 gg(16, 4, 8);
    gemm256<<<gg, 256, 0, stream>>>(Wq, bq, x, qb);
    offset_kernel<<<128, 256, 0, stream>>>(qb, odw, odb, olg, olb, opw, pos);
    sample_kernel<<<8192, 256, 0, stream>>>(x, pos, xs);
    gemm256<<<gg, 256, 0, stream>>>(Wk, bk, xs, kb);
    gemm256<<<gg, 256, 0, stream>>>(Wv, bv, xs, vb);
    lepe_kernel<<<8192, 256, 0, stream>>>(qb, rdw, rdb, lep);
    attn_kernel<<<dim3(16, 64), 256, 0, stream>>>(qb, kb, vb, lep, aout);
    gemm256<<<gg, 256, 0, stream>>>(Wo, bo, aout, y);
}

// Round 2
// 243.585 us; speedup vs baseline: 1.8899x; 1.8899x over previous
//
#include <hip/hip_runtime.h>
#include <math.h>

// Bottleneck_49039936586369: deformable attention, bf16-MFMA version.
// B=8, C=256, H=W=32, heads=8 (HC=32), groups=4 (GC=64), n=1024.

#define NPOS 1024

typedef float f32x4   __attribute__((ext_vector_type(4)));
typedef short bf16x8  __attribute__((ext_vector_type(8)));
typedef short short4v __attribute__((ext_vector_type(4)));

__device__ __forceinline__ short f2bf(float f) {
    unsigned u = __float_as_uint(f);
    unsigned r = (u + 0x7FFFu + ((u >> 16) & 1u)) >> 16;   // RNE
    return (short)r;
}

// Load one MFMA operand fragment (two-half k mapping) from an LDS tile with
// row length KE shorts and per-row b64-slot XOR swizzle.
__device__ __forceinline__ bf16x8 ldfrag(const short* base, int row, int KE,
                                         int s0, int s1, int swz) {
    const short* r = base + row * KE;
    short4v lo = *(const short4v*)(r + ((s0 ^ swz) << 2));
    short4v hi = *(const short4v*)(r + ((s1 ^ swz) << 2));
    bf16x8 f = {lo[0], lo[1], lo[2], lo[3], hi[0], hi[1], hi[2], hi[3]};
    return f;
}

// Store 8 bf16 (global b128 payload = slots 2h,2h+1) into swizzled LDS tile.
__device__ __forceinline__ void stpair(short* base, int row, int KE, int h, int swz,
                                       bf16x8 v8) {
    short4v lo = {v8[0], v8[1], v8[2], v8[3]};
    short4v hi = {v8[4], v8[5], v8[6], v8[7]};
    *(short4v*)(base + row * KE + (((2 * h) ^ swz) << 2)) = lo;
    *(short4v*)(base + row * KE + (((2 * h + 1) ^ swz) << 2)) = hi;
}

// ---------------------------------------------------------------------------
// Cast the four 256x256 weight matrices to bf16 (contiguous: q,k,v,o).
// ---------------------------------------------------------------------------
__global__ void cvt_w(const float* __restrict__ Wq, const float* __restrict__ Wk,
                      const float* __restrict__ Wv, const float* __restrict__ Wo,
                      short* __restrict__ Wb)
{
    int gid = blockIdx.x * 256 + threadIdx.x;      // 262144
    const float* src = (gid < 65536) ? Wq : (gid < 131072) ? Wk
                     : (gid < 196608) ? Wv : Wo;
    Wb[gid] = f2bf(src[gid & 65535]);
}

// ---------------------------------------------------------------------------
// xT[b][p][c] bf16  <-  x[b][c][p] fp32.  grid(16,4,8), 64x64 tiles.
// ---------------------------------------------------------------------------
__global__ __launch_bounds__(256) void transpose_x(const float* __restrict__ x,
                                                   short* __restrict__ xT)
{
    __shared__ float tile[64][69];
    const int p0 = blockIdx.x * 64, c0 = blockIdx.y * 64, b = blockIdx.z;
    const int t = threadIdx.x;
    #pragma unroll
    for (int i = 0; i < 4; ++i) {
        int id = t + i * 256;              // 64 rows x 16 float4
        int row = id >> 4, q = id & 15;
        float4 v = *(const float4*)(x + ((long)(b * 256 + c0 + row)) * NPOS + p0 + q * 4);
        tile[row][q * 4 + 0] = v.x; tile[row][q * 4 + 1] = v.y;
        tile[row][q * 4 + 2] = v.z; tile[row][q * 4 + 3] = v.w;
    }
    __syncthreads();
    #pragma unroll
    for (int i = 0; i < 2; ++i) {
        int id = t + i * 256;              // 64 p x 8 cgroups
        int p = id >> 3, cg = id & 7;
        bf16x8 o;
        #pragma unroll
        for (int j = 0; j < 8; ++j) o[j] = f2bf(tile[cg * 8 + j][p]);
        *(bf16x8*)(xT + ((long)(b * 1024 + p0 + p)) * 256 + c0 + cg * 8) = o;
    }
}

// ---------------------------------------------------------------------------
// bf16 MFMA GEMM: Y[b] = W(256x256) @ X[b](256x1024) + bias.
// A = Wb [m][k] bf16;  B = Xt [b][n][k] bf16 (n-major).  grid(16,4,8), 4 waves.
// MODE 0: fp32 q natural + bf16 qT[bh][n][hc] (scaled);  1: bf16 kT;
// MODE 2: bf16 v natural;  3: fp32 y natural.
// ---------------------------------------------------------------------------
template<int MODE>
__global__ __launch_bounds__(256) void gemm_mfma(
    const short* __restrict__ A, const short* __restrict__ Bt,
    const float* __restrict__ bias,
    float* __restrict__ outF, short* __restrict__ outT, short* __restrict__ outN)
{
    __shared__ short As[64 * 64];
    __shared__ short Bs[64 * 64];
    const int t = threadIdx.x;
    const int n0 = blockIdx.x * 64, m0 = blockIdx.y * 64;
    const int b = blockIdx.z;
    const int lane = t & 63, w = t >> 6;
    const int wm = w >> 1, wn = w & 1;
    const int l15 = lane & 15, g = lane >> 4;
    f32x4 z = {0.f, 0.f, 0.f, 0.f};
    f32x4 acc[2][2];
    acc[0][0] = z; acc[0][1] = z; acc[1][0] = z; acc[1][1] = z;

    for (int kt = 0; kt < 4; ++kt) {
        const int k0 = kt * 64;
        __syncthreads();
        #pragma unroll
        for (int i = 0; i < 2; ++i) {
            int q = t + i * 256;           // 512 chunks per tile
            int row = q >> 3, p = q & 7;
            bf16x8 av = *(const bf16x8*)(A + (long)(m0 + row) * 256 + k0 + p * 8);
            stpair(As, row, 64, p, row & 15, av);
            bf16x8 bv = *(const bf16x8*)(Bt + ((long)b * 1024 + n0 + row) * 256 + k0 + p * 8);
            stpair(Bs, row, 64, p, row & 15, bv);
        }
        __syncthreads();
        #pragma unroll
        for (int kk = 0; kk < 2; ++kk) {
            bf16x8 af[2], bfr[2];
            #pragma unroll
            for (int mi = 0; mi < 2; ++mi) {
                int row = wm * 32 + mi * 16 + l15;
                af[mi] = ldfrag(As, row, 64, kk * 8 + g, kk * 8 + 4 + g, row & 15);
            }
            #pragma unroll
            for (int ni = 0; ni < 2; ++ni) {
                int row = wn * 32 + ni * 16 + l15;
                bfr[ni] = ldfrag(Bs, row, 64, kk * 8 + g, kk * 8 + 4 + g, row & 15);
            }
            #pragma unroll
            for (int mi = 0; mi < 2; ++mi)
                #pragma unroll
                for (int ni = 0; ni < 2; ++ni)
                    acc[mi][ni] = __builtin_amdgcn_mfma_f32_16x16x32_bf16(
                        af[mi], bfr[ni], acc[mi][ni], 0, 0, 0);
        }
    }
    // epilogue: m = m0+wm*32+mi*16+g*4+j, n = n0+wn*32+ni*16+l15
    #pragma unroll
    for (int mi = 0; mi < 2; ++mi) {
        const int mbase = m0 + wm * 32 + mi * 16 + g * 4;
        float bv[4];
        #pragma unroll
        for (int j = 0; j < 4; ++j) bv[j] = bias[mbase + j];
        #pragma unroll
        for (int ni = 0; ni < 2; ++ni) {
            const int n = n0 + wn * 32 + ni * 16 + l15;
            f32x4 r = acc[mi][ni];
            #pragma unroll
            for (int j = 0; j < 4; ++j) r[j] += bv[j];
            if constexpr (MODE == 0 || MODE == 3) {
                #pragma unroll
                for (int j = 0; j < 4; ++j)
                    outF[((long)b * 256 + mbase + j) * NPOS + n] = r[j];
            }
            if constexpr (MODE == 0) {
                const float sc = 0.17677669529663687f;   // HC^-0.5
                short4v p = {f2bf(r[0] * sc), f2bf(r[1] * sc),
                             f2bf(r[2] * sc), f2bf(r[3] * sc)};
                int bh = b * 8 + (mbase >> 5);
                *(short4v*)(outT + ((long)bh * 1024 + n) * 32 + (mbase & 31)) = p;
            }
            if constexpr (MODE == 1) {
                short4v p = {f2bf(r[0]), f2bf(r[1]), f2bf(r[2]), f2bf(r[3])};
                int bh = b * 8 + (mbase >> 5);
                *(short4v*)(outT + ((long)bh * 1024 + n) * 32 + (mbase & 31)) = p;
            }
            if constexpr (MODE == 2) {
                #pragma unroll
                for (int j = 0; j < 4; ++j)
                    outN[((long)b * 256 + mbase + j) * NPOS + n] = f2bf(r[j]);
            }
        }
    }
}

// ---------------------------------------------------------------------------
// depthwise 3x3 helper (zero pad, 32x32 image)
// ---------------------------------------------------------------------------
__device__ __forceinline__ float conv3(const float* __restrict__ img,
                                       const float* __restrict__ w, int y, int x)
{
    float acc = 0.f;
    #pragma unroll
    for (int dy = 0; dy < 3; ++dy) {
        int yy = y + dy - 1;
        if (yy < 0 || yy > 31) continue;
        #pragma unroll
        for (int dx = 0; dx < 3; ++dx) {
            int xx = x + dx - 1;
            if (xx < 0 || xx > 31) continue;
            acc += w[dy * 3 + dx] * img[yy * 32 + xx];
        }
    }
    return acc;
}

// ---------------------------------------------------------------------------
// Offset branch (fp32, reads fp32 q): dwconv3x3 -> LN -> GELU -> pw -> tanh.
// ---------------------------------------------------------------------------
__global__ void offset_kernel(const float* __restrict__ q,
    const float* __restrict__ dww, const float* __restrict__ dwb,
    const float* __restrict__ lng, const float* __restrict__ lnb,
    const float* __restrict__ pww, float* __restrict__ pos)
{
    int gid = blockIdx.x * 256 + threadIdx.x;     // 32*1024
    int p = gid & 1023, bg = gid >> 10;
    int yy = p >> 5, xx = p & 31;
    const float* qb = q + (long)bg * 64 * NPOS;
    float s = 0.f, s2 = 0.f;
    for (int c = 0; c < 64; ++c) {
        float oc = conv3(qb + (long)c * NPOS, dww + c * 9, yy, xx) + dwb[c];
        s += oc; s2 += oc * oc;
    }
    float mu = s * 0.015625f;
    float var = s2 * 0.015625f - mu * mu;
    float rstd = rsqrtf(var + 1e-5f);
    float a0 = 0.f, a1 = 0.f;
    for (int c = 0; c < 64; ++c) {
        float oc = conv3(qb + (long)c * NPOS, dww + c * 9, yy, xx) + dwb[c];
        float on = (oc - mu) * rstd * lng[c] + lnb[c];
        float ge = 0.5f * on * (1.f + erff(on * 0.70710678118654752f));
        a0 += pww[c] * ge;
        a1 += pww[64 + c] * ge;
    }
    const float rng = 4.f / 31.f;
    float offy = tanhf(a0) * rng;
    float offx = tanhf(a1) * rng;
    float ry = ((yy + 0.5f) / 31.f) * 2.f - 1.f;
    float rx = ((xx + 0.5f) / 31.f) * 2.f - 1.f;
    pos[(long)bg * 2048 + p * 2 + 0] = offy + ry;
    pos[(long)bg * 2048 + p * 2 + 1] = offx + rx;
}

// ---------------------------------------------------------------------------
// Bilinear grid-sample -> bf16 xsT[b][p][c] (c fastest for coalesced writes).
// ---------------------------------------------------------------------------
__global__ void sample_kernel(const float* __restrict__ x,
    const float* __restrict__ pos, short* __restrict__ xsT)
{
    int gid = blockIdx.x * 256 + threadIdx.x;     // 2^21
    int cc = gid & 63;
    int p  = (gid >> 6) & 1023;
    int bg = gid >> 16;
    float py = pos[(long)bg * 2048 + p * 2 + 0];
    float px = pos[(long)bg * 2048 + p * 2 + 1];
    float fy = (py + 1.f) * 15.5f;
    float fx = (px + 1.f) * 15.5f;
    float y0f = floorf(fy), x0f = floorf(fx);
    int y0 = (int)y0f, x0 = (int)x0f;
    float yw = fy - y0f, xw = fx - x0f;
    const float* img = x + ((long)bg * 64 + cc) * NPOS;
    float acc = 0.f;
    { int yi = y0,     xi = x0;     float wg = (1.f - yw) * (1.f - xw);
      if (yi >= 0 && yi < 32 && xi >= 0 && xi < 32) acc += wg * img[yi * 32 + xi]; }
    { int yi = y0,     xi = x0 + 1; float wg = (1.f - yw) * xw;
      if (yi >= 0 && yi < 32 && xi >= 0 && xi < 32) acc += wg * img[yi * 32 + xi]; }
    { int yi = y0 + 1, xi = x0;     float wg = yw * (1.f - xw);
      if (yi >= 0 && yi < 32 && xi >= 0 && xi < 32) acc += wg * img[yi * 32 + xi]; }
    { int yi = y0 + 1, xi = x0 + 1; float wg = yw * xw;
      if (yi >= 0 && yi < 32 && xi >= 0 && xi < 32) acc += wg * img[yi * 32 + xi]; }
    xsT[((long)(bg >> 2) * 1024 + p) * 256 + (bg & 3) * 64 + cc] = f2bf(acc);
}

// ---------------------------------------------------------------------------
// lepe = dwconv3x3(q) + bias, fp32 [b][c][p].
// ---------------------------------------------------------------------------
__global__ void lepe_kernel(const float* __restrict__ q,
    const float* __restrict__ w, const float* __restrict__ b,
    float* __restrict__ lepe)
{
    int gid = blockIdx.x * 256 + threadIdx.x;     // 2^21
    int p = gid & 1023;
    int c = (gid >> 10) & 255;
    int yy = p >> 5, xx = p & 31;
    const float* img = q + (long)(gid - p);
    lepe[gid] = conv3(img, w + c * 9, yy, xx) + b[c];
}

// ---------------------------------------------------------------------------
// MFMA flash attention (T12 swapped-operand).  grid(16 mt, 64 bh), 4 waves.
// Per wave: 16 queries; S^T = mfma(K,Q) so each lane owns one query column;
// P^T B-frags for PV = mfma(V,P^T) come straight from S^T accum registers.
// Epilogue fuses +lepe and writes bf16 aoutT[b][p][c].
// ---------------------------------------------------------------------------
__global__ __launch_bounds__(256) void attn_mfma(
    const short* __restrict__ qT, const short* __restrict__ kT,
    const short* __restrict__ vN, const float* __restrict__ lep,
    short* __restrict__ aoutT)
{
    __shared__ short qS[64 * 32];
    __shared__ short kS[64 * 32];
    __shared__ short vS[32 * 64];
    __shared__ float oT[64 * 33];
    const int t = threadIdx.x;
    const int mt = blockIdx.x, bh = blockIdx.y;
    const int m0 = mt * 64;
    const int lane = t & 63, w = t >> 6;
    const int l15 = lane & 15, g = lane >> 4;
    const long base32 = (long)bh * 32768;          // bh*1024*32 == bh*32*1024
    f32x4 z = {0.f, 0.f, 0.f, 0.f};

    // stage Q tile (64 x 32)
    {
        int row = t >> 2, h = t & 3;
        bf16x8 v8 = *(const bf16x8*)(qT + base32 + (long)(m0 + row) * 32 + h * 8);
        stpair(qS, row, 32, h, (row >> 1) & 7, v8);
    }
    __syncthreads();
    const int qrow = w * 16 + l15;
    const bf16x8 qb = ldfrag(qS, qrow, 32, g, 4 + g, (qrow >> 1) & 7);

    float Mr = -1e30f, Lr = 0.f;
    f32x4 po[2]; po[0] = z; po[1] = z;

    for (int nt = 0; nt < 16; ++nt) {
        const int n0 = nt * 64;
        __syncthreads();
        {   // stage K^T tile (64n x 32c) and V tile (32c x 64n)
            int row = t >> 2, h = t & 3;
            bf16x8 v8 = *(const bf16x8*)(kT + base32 + (long)(n0 + row) * 32 + h * 8);
            stpair(kS, row, 32, h, (row >> 1) & 7, v8);
            int c = t >> 3, h2 = t & 7;
            bf16x8 u8 = *(const bf16x8*)(vN + base32 + (long)c * NPOS + n0 + h2 * 8);
            stpair(vS, c, 64, h2, c & 15, u8);
        }
        __syncthreads();
        // S^T: 4 frags (16n each), K=32 in one mfma
        f32x4 s[4];
        #pragma unroll
        for (int j = 0; j < 4; ++j) {
            int krow = j * 16 + l15;
            bf16x8 ka = ldfrag(kS, krow, 32, g, 4 + g, (krow >> 1) & 7);
            s[j] = __builtin_amdgcn_mfma_f32_16x16x32_bf16(ka, qb, z, 0, 0, 0);
        }
        // online softmax: lane owns query m = w*16+l15; partners at lane^16, ^32
        float mx = -1e30f;
        #pragma unroll
        for (int j = 0; j < 4; ++j)
            #pragma unroll
            for (int r = 0; r < 4; ++r) mx = fmaxf(mx, s[j][r]);
        mx = fmaxf(mx, __shfl_xor(mx, 16));
        mx = fmaxf(mx, __shfl_xor(mx, 32));
        float Mn = fmaxf(Mr, mx);
        float esc = __expf(Mr - Mn);
        Mr = Mn;
        float ls = 0.f;
        #pragma unroll
        for (int j = 0; j < 4; ++j)
            #pragma unroll
            for (int r = 0; r < 4; ++r) { s[j][r] = __expf(s[j][r] - Mn); ls += s[j][r]; }
        ls += __shfl_xor(ls, 16);
        ls += __shfl_xor(ls, 32);
        Lr = Lr * esc + ls;
        po[0] *= esc; po[1] *= esc;
        // P^T B-frags straight from S^T registers
        bf16x8 pb[2];
        #pragma unroll
        for (int ks = 0; ks < 2; ++ks)
            #pragma unroll
            for (int e = 0; e < 4; ++e) {
                pb[ks][e]     = f2bf(s[2 * ks][e]);
                pb[ks][4 + e] = f2bf(s[2 * ks + 1][e]);
            }
        // PV: O^T[c][m] += V[c][n] * P^T[n][m]
        #pragma unroll
        for (int cs = 0; cs < 2; ++cs) {
            int vrow = cs * 16 + l15;
            #pragma unroll
            for (int ks = 0; ks < 2; ++ks) {
                bf16x8 va = ldfrag(vS, vrow, 64, ks * 8 + g, ks * 8 + 4 + g, vrow & 15);
                po[cs] = __builtin_amdgcn_mfma_f32_16x16x32_bf16(va, pb[ks], po[cs], 0, 0, 0);
            }
        }
    }
    // epilogue: oT[m][c] then fused +lepe -> bf16 aoutT[b][p][c]
    float inv = 1.f / Lr;
    #pragma unroll
    for (int cs = 0; cs < 2; ++cs)
        #pragma unroll
        for (int r = 0; r < 4; ++r)
            oT[(w * 16 + l15) * 33 + cs * 16 + g * 4 + r] = po[cs][r] * inv;
    __syncthreads();
    #pragma unroll
    for (int i = 0; i < 8; ++i) {
        int idx = t + i * 256;
        int c = idx & 31, m = idx >> 5;
        float v = oT[m * 33 + c] + lep[base32 + (long)c * NPOS + m0 + m];
        aoutT[(((long)(bh >> 3)) * 1024 + m0 + m) * 256 + (bh & 7) * 32 + c] = f2bf(v);
    }
}

// ---------------------------------------------------------------------------
extern "C" void kernel_launch(void* const* d_in, const int* in_sizes, int n_in,
                              void* d_out, int out_size, void* d_ws, size_t ws_size,
                              hipStream_t stream)
{
    const float* x   = (const float*)d_in[0];
    const float* Wq  = (const float*)d_in[1];
    const float* bq  = (const float*)d_in[2];
    const float* Wk  = (const float*)d_in[3];
    const float* bk  = (const float*)d_in[4];
    const float* Wv  = (const float*)d_in[5];
    const float* bv  = (const float*)d_in[6];
    const float* Wo  = (const float*)d_in[7];
    const float* bo  = (const float*)d_in[8];
    const float* odw = (const float*)d_in[9];
    const float* odb = (const float*)d_in[10];
    const float* olg = (const float*)d_in[11];
    const float* olb = (const float*)d_in[12];
    const float* opw = (const float*)d_in[13];
    const float* rdw = (const float*)d_in[14];
    const float* rdb = (const float*)d_in[15];

    float* ws = (float*)d_ws;
    const size_t SZ = (size_t)2097152;            // 2M elements per big buffer
    float* qf  = ws;                              // fp32 q  [8][256][1024]
    float* lep = ws + SZ;                         // fp32 lepe
    float* pos = ws + 2 * SZ;                     // 65536 floats
    short* sb  = (short*)(ws + 2 * SZ + 65536);   // bf16 region (16B aligned)
    short* Wb  = sb;                              // 4 x 65536
    short* xT  = Wb + 262144;                     // [8][1024][256]
    short* xsT = xT + SZ;                         // [8][1024][256]
    short* qTb = xsT + SZ;                        // [64][1024][32]
    short* kTb = qTb + SZ;                        // [64][1024][32]
    short* vNb = kTb + SZ;                        // [8][256][1024]
    short* aoT = xT;                              // alias: xT dead after q GEMM
    float* y   = (float*)d_out;

    dim3 gg(16, 4, 8);
    cvt_w<<<1024, 256, 0, stream>>>(Wq, Wk, Wv, Wo, Wb);
    transpose_x<<<gg, 256, 0, stream>>>(x, xT);
    gemm_mfma<0><<<gg, 256, 0, stream>>>(Wb,          xT,  bq, qf,      qTb, nullptr);
    offset_kernel<<<128, 256, 0, stream>>>(qf, odw, odb, olg, olb, opw, pos);
    sample_kernel<<<8192, 256, 0, stream>>>(x, pos, xsT);
    gemm_mfma<1><<<gg, 256, 0, stream>>>(Wb + 65536,  xsT, bk, nullptr, kTb, nullptr);
    gemm_mfma<2><<<gg, 256, 0, stream>>>(Wb + 131072, xsT, bv, nullptr, nullptr, vNb);
    lepe_kernel<<<8192, 256, 0, stream>>>(qf, rdw, rdb, lep);
    attn_mfma<<<dim3(16, 64), 256, 0, stream>>>(qTb, kTb, vNb, lep, aoT);
    gemm_mfma<3><<<gg, 256, 0, stream>>>(Wb + 196608, aoT, bo, y, nullptr, nullptr);
}

// Round 3
// 126.445 us; speedup vs baseline: 3.6407x; 1.9264x over previous
//
#include <hip/hip_runtime.h>
#include <math.h>

// Bottleneck_49039936586369: deformable attention, bf16-MFMA version.
// B=8, C=256, H=W=32, heads=8 (HC=32), groups=4 (GC=64), n=1024.

#define NPOS 1024

typedef float f32x4   __attribute__((ext_vector_type(4)));
typedef short bf16x8  __attribute__((ext_vector_type(8)));
typedef short short4v __attribute__((ext_vector_type(4)));

__device__ __forceinline__ short f2bf(float f) {
    unsigned u = __float_as_uint(f);
    unsigned r = (u + 0x7FFFu + ((u >> 16) & 1u)) >> 16;   // RNE
    return (short)r;
}

// Load one MFMA operand fragment (two-half k mapping) from an LDS tile with
// row length KE shorts and per-row b64-slot XOR swizzle.
__device__ __forceinline__ bf16x8 ldfrag(const short* base, int row, int KE,
                                         int s0, int s1, int swz) {
    const short* r = base + row * KE;
    short4v lo = *(const short4v*)(r + ((s0 ^ swz) << 2));
    short4v hi = *(const short4v*)(r + ((s1 ^ swz) << 2));
    bf16x8 f = {lo[0], lo[1], lo[2], lo[3], hi[0], hi[1], hi[2], hi[3]};
    return f;
}

// Store 8 bf16 (global b128 payload = slots 2h,2h+1) into swizzled LDS tile.
__device__ __forceinline__ void stpair(short* base, int row, int KE, int h, int swz,
                                       bf16x8 v8) {
    short4v lo = {v8[0], v8[1], v8[2], v8[3]};
    short4v hi = {v8[4], v8[5], v8[6], v8[7]};
    *(short4v*)(base + row * KE + (((2 * h) ^ swz) << 2)) = lo;
    *(short4v*)(base + row * KE + (((2 * h + 1) ^ swz) << 2)) = hi;
}

// ---------------------------------------------------------------------------
// Cast the four 256x256 weight matrices to bf16 (contiguous: q,k,v,o).
// ---------------------------------------------------------------------------
__global__ void cvt_w(const float* __restrict__ Wq, const float* __restrict__ Wk,
                      const float* __restrict__ Wv, const float* __restrict__ Wo,
                      short* __restrict__ Wb)
{
    int gid = blockIdx.x * 256 + threadIdx.x;      // 262144
    const float* src = (gid < 65536) ? Wq : (gid < 131072) ? Wk
                     : (gid < 196608) ? Wv : Wo;
    Wb[gid] = f2bf(src[gid & 65535]);
}

// ---------------------------------------------------------------------------
// xT[b][p][c] bf16  <-  x[b][c][p] fp32.  grid(16,4,8), 64x64 tiles.
// ---------------------------------------------------------------------------
__global__ __launch_bounds__(256) void transpose_x(const float* __restrict__ x,
                                                   short* __restrict__ xT)
{
    __shared__ float tile[64][69];
    const int p0 = blockIdx.x * 64, c0 = blockIdx.y * 64, b = blockIdx.z;
    const int t = threadIdx.x;
    #pragma unroll
    for (int i = 0; i < 4; ++i) {
        int id = t + i * 256;              // 64 rows x 16 float4
        int row = id >> 4, q = id & 15;
        float4 v = *(const float4*)(x + ((long)(b * 256 + c0 + row)) * NPOS + p0 + q * 4);
        tile[row][q * 4 + 0] = v.x; tile[row][q * 4 + 1] = v.y;
        tile[row][q * 4 + 2] = v.z; tile[row][q * 4 + 3] = v.w;
    }
    __syncthreads();
    #pragma unroll
    for (int i = 0; i < 2; ++i) {
        int id = t + i * 256;              // 64 p x 8 cgroups
        int p = id >> 3, cg = id & 7;
        bf16x8 o;
        #pragma unroll
        for (int j = 0; j < 8; ++j) o[j] = f2bf(tile[cg * 8 + j][p]);
        *(bf16x8*)(xT + ((long)(b * 1024 + p0 + p)) * 256 + c0 + cg * 8) = o;
    }
}

// ---------------------------------------------------------------------------
// bf16 MFMA GEMM: Y[b] = W(256x256) @ X[b](256x1024) + bias.
// A = Wb [m][k] bf16;  B = Xt [b][n][k] bf16 (n-major).  grid(16,4,8), 4 waves.
// MODE 0: fp32 q natural + bf16 qT[bh][n][hc] (scaled);  1: bf16 kT;
// MODE 2: bf16 v natural;  3: fp32 y natural.
// ---------------------------------------------------------------------------
template<int MODE>
__global__ __launch_bounds__(256) void gemm_mfma(
    const short* __restrict__ A, const short* __restrict__ Bt,
    const float* __restrict__ bias,
    float* __restrict__ outF, short* __restrict__ outT, short* __restrict__ outN)
{
    __shared__ short As[64 * 64];
    __shared__ short Bs[64 * 64];
    const int t = threadIdx.x;
    const int n0 = blockIdx.x * 64, m0 = blockIdx.y * 64;
    const int b = blockIdx.z;
    const int lane = t & 63, w = t >> 6;
    const int wm = w >> 1, wn = w & 1;
    const int l15 = lane & 15, g = lane >> 4;
    f32x4 z = {0.f, 0.f, 0.f, 0.f};
    f32x4 acc[2][2];
    acc[0][0] = z; acc[0][1] = z; acc[1][0] = z; acc[1][1] = z;

    for (int kt = 0; kt < 4; ++kt) {
        const int k0 = kt * 64;
        __syncthreads();
        #pragma unroll
        for (int i = 0; i < 2; ++i) {
            int q = t + i * 256;           // 512 chunks per tile
            int row = q >> 3, p = q & 7;
            bf16x8 av = *(const bf16x8*)(A + (long)(m0 + row) * 256 + k0 + p * 8);
            stpair(As, row, 64, p, row & 15, av);
            bf16x8 bv = *(const bf16x8*)(Bt + ((long)b * 1024 + n0 + row) * 256 + k0 + p * 8);
            stpair(Bs, row, 64, p, row & 15, bv);
        }
        __syncthreads();
        #pragma unroll
        for (int kk = 0; kk < 2; ++kk) {
            bf16x8 af[2], bfr[2];
            #pragma unroll
            for (int mi = 0; mi < 2; ++mi) {
                int row = wm * 32 + mi * 16 + l15;
                af[mi] = ldfrag(As, row, 64, kk * 8 + g, kk * 8 + 4 + g, row & 15);
            }
            #pragma unroll
            for (int ni = 0; ni < 2; ++ni) {
                int row = wn * 32 + ni * 16 + l15;
                bfr[ni] = ldfrag(Bs, row, 64, kk * 8 + g, kk * 8 + 4 + g, row & 15);
            }
            #pragma unroll
            for (int mi = 0; mi < 2; ++mi)
                #pragma unroll
                for (int ni = 0; ni < 2; ++ni)
                    acc[mi][ni] = __builtin_amdgcn_mfma_f32_16x16x32_bf16(
                        af[mi], bfr[ni], acc[mi][ni], 0, 0, 0);
        }
    }
    // epilogue: m = m0+wm*32+mi*16+g*4+j, n = n0+wn*32+ni*16+l15
    #pragma unroll
    for (int mi = 0; mi < 2; ++mi) {
        const int mbase = m0 + wm * 32 + mi * 16 + g * 4;
        float bv[4];
        #pragma unroll
        for (int j = 0; j < 4; ++j) bv[j] = bias[mbase + j];
        #pragma unroll
        for (int ni = 0; ni < 2; ++ni) {
            const int n = n0 + wn * 32 + ni * 16 + l15;
            f32x4 r = acc[mi][ni];
            #pragma unroll
            for (int j = 0; j < 4; ++j) r[j] += bv[j];
            if constexpr (MODE == 0 || MODE == 3) {
                #pragma unroll
                for (int j = 0; j < 4; ++j)
                    outF[((long)b * 256 + mbase + j) * NPOS + n] = r[j];
            }
            if constexpr (MODE == 0) {
                const float sc = 0.17677669529663687f;   // HC^-0.5
                short4v p = {f2bf(r[0] * sc), f2bf(r[1] * sc),
                             f2bf(r[2] * sc), f2bf(r[3] * sc)};
                int bh = b * 8 + (mbase >> 5);
                *(short4v*)(outT + ((long)bh * 1024 + n) * 32 + (mbase & 31)) = p;
            }
            if constexpr (MODE == 1) {
                short4v p = {f2bf(r[0]), f2bf(r[1]), f2bf(r[2]), f2bf(r[3])};
                int bh = b * 8 + (mbase >> 5);
                *(short4v*)(outT + ((long)bh * 1024 + n) * 32 + (mbase & 31)) = p;
            }
            if constexpr (MODE == 2) {
                #pragma unroll
                for (int j = 0; j < 4; ++j)
                    outN[((long)b * 256 + mbase + j) * NPOS + n] = f2bf(r[j]);
            }
        }
    }
}

// ---------------------------------------------------------------------------
// Offset branch, cooperative: one block per (bg, image row y).
// grid(32 y, 32 bg), 256 threads: thread (p = t>>3, cg = t&7) computes the
// dwconv for 8 channels of pixel (y,p) into registers; LN stats + pointwise
// reduce via shfl_xor over the 8-lane cg group.
// ---------------------------------------------------------------------------
__global__ __launch_bounds__(256) void offset_kernel(const float* __restrict__ q,
    const float* __restrict__ dww, const float* __restrict__ dwb,
    const float* __restrict__ lng, const float* __restrict__ lnb,
    const float* __restrict__ pww, float* __restrict__ pos)
{
    __shared__ float q3[64][3][33];   // [c][row][x], pad 33: cg-stride free 2-way
    __shared__ float wS[576];
    __shared__ float bS[64], gS[64], lbS[64], pS[128];
    const int t = threadIdx.x;
    const int y = blockIdx.x, bg = blockIdx.y;
    const float* qb = q + (long)bg * 64 * NPOS;
    // stage weights
    for (int i = t; i < 576; i += 256) wS[i] = dww[i];
    if (t < 64) { bS[t] = dwb[t]; gS[t] = lng[t]; lbS[t] = lnb[t]; }
    else if (t >= 128 && t < 256) pS[t - 128] = pww[t - 128];
    // stage 3 rows x 64 ch (zero-padded at y edges)
    #pragma unroll
    for (int i = 0; i < 6; ++i) {
        int id = t + i * 256;                 // 0..1535 = 64c x 3r x 8 float4
        int c = id / 24, rx = id - c * 24;
        int r = rx >> 3, q4 = (rx & 7) * 4;
        int yy = y + r - 1;
        float4 v = make_float4(0.f, 0.f, 0.f, 0.f);
        if (yy >= 0 && yy < 32)
            v = *(const float4*)(qb + (long)c * NPOS + yy * 32 + q4);
        q3[c][r][q4 + 0] = v.x; q3[c][r][q4 + 1] = v.y;
        q3[c][r][q4 + 2] = v.z; q3[c][r][q4 + 3] = v.w;
    }
    __syncthreads();
    const int p = t >> 3, cg = t & 7;
    float oc[8];
    float s = 0.f, s2 = 0.f;
    #pragma unroll
    for (int j = 0; j < 8; ++j) {
        int c = cg * 8 + j;
        float acc = bS[c];
        #pragma unroll
        for (int dy = 0; dy < 3; ++dy)
            #pragma unroll
            for (int dx = 0; dx < 3; ++dx) {
                int xx = p + dx - 1;
                if (xx >= 0 && xx < 32)
                    acc += wS[c * 9 + dy * 3 + dx] * q3[c][dy][xx];
            }
        oc[j] = acc;
        s += acc; s2 += acc * acc;
    }
    s  += __shfl_xor(s, 1);  s  += __shfl_xor(s, 2);  s  += __shfl_xor(s, 4);
    s2 += __shfl_xor(s2, 1); s2 += __shfl_xor(s2, 2); s2 += __shfl_xor(s2, 4);
    float mu = s * 0.015625f;
    float var = s2 * 0.015625f - mu * mu;
    float rstd = rsqrtf(var + 1e-5f);
    float a0 = 0.f, a1 = 0.f;
    #pragma unroll
    for (int j = 0; j < 8; ++j) {
        int c = cg * 8 + j;
        float on = (oc[j] - mu) * rstd * gS[c] + lbS[c];
        float ge = 0.5f * on * (1.f + erff(on * 0.70710678118654752f));
        a0 += pS[c] * ge;
        a1 += pS[64 + c] * ge;
    }
    a0 += __shfl_xor(a0, 1); a0 += __shfl_xor(a0, 2); a0 += __shfl_xor(a0, 4);
    a1 += __shfl_xor(a1, 1); a1 += __shfl_xor(a1, 2); a1 += __shfl_xor(a1, 4);
    if (cg == 0) {
        const float rng = 4.f / 31.f;
        float offy = tanhf(a0) * rng;
        float offx = tanhf(a1) * rng;
        float ry = ((y + 0.5f) / 31.f) * 2.f - 1.f;
        float rx = ((p + 0.5f) / 31.f) * 2.f - 1.f;
        int pp = y * 32 + p;
        pos[(long)bg * 2048 + pp * 2 + 0] = offy + ry;
        pos[(long)bg * 2048 + pp * 2 + 1] = offx + rx;
    }
}

// ---------------------------------------------------------------------------
// Bilinear grid-sample -> bf16 xsT[b][p][c] (c fastest for coalesced writes).
// ---------------------------------------------------------------------------
__global__ void sample_kernel(const float* __restrict__ x,
    const float* __restrict__ pos, short* __restrict__ xsT)
{
    int gid = blockIdx.x * 256 + threadIdx.x;     // 2^21
    int cc = gid & 63;
    int p  = (gid >> 6) & 1023;
    int bg = gid >> 16;
    float py = pos[(long)bg * 2048 + p * 2 + 0];
    float px = pos[(long)bg * 2048 + p * 2 + 1];
    float fy = (py + 1.f) * 15.5f;
    float fx = (px + 1.f) * 15.5f;
    float y0f = floorf(fy), x0f = floorf(fx);
    int y0 = (int)y0f, x0 = (int)x0f;
    float yw = fy - y0f, xw = fx - x0f;
    const float* img = x + ((long)bg * 64 + cc) * NPOS;
    float acc = 0.f;
    { int yi = y0,     xi = x0;     float wg = (1.f - yw) * (1.f - xw);
      if (yi >= 0 && yi < 32 && xi >= 0 && xi < 32) acc += wg * img[yi * 32 + xi]; }
    { int yi = y0,     xi = x0 + 1; float wg = (1.f - yw) * xw;
      if (yi >= 0 && yi < 32 && xi >= 0 && xi < 32) acc += wg * img[yi * 32 + xi]; }
    { int yi = y0 + 1, xi = x0;     float wg = yw * (1.f - xw);
      if (yi >= 0 && yi < 32 && xi >= 0 && xi < 32) acc += wg * img[yi * 32 + xi]; }
    { int yi = y0 + 1, xi = x0 + 1; float wg = yw * xw;
      if (yi >= 0 && yi < 32 && xi >= 0 && xi < 32) acc += wg * img[yi * 32 + xi]; }
    xsT[((long)(bg >> 2) * 1024 + p) * 256 + (bg & 3) * 64 + cc] = f2bf(acc);
}

// ---------------------------------------------------------------------------
// depthwise 3x3 helper (zero pad, 32x32 image)
// ---------------------------------------------------------------------------
__device__ __forceinline__ float conv3(const float* __restrict__ img,
                                       const float* __restrict__ w, int y, int x)
{
    float acc = 0.f;
    #pragma unroll
    for (int dy = 0; dy < 3; ++dy) {
        int yy = y + dy - 1;
        if (yy < 0 || yy > 31) continue;
        #pragma unroll
        for (int dx = 0; dx < 3; ++dx) {
            int xx = x + dx - 1;
            if (xx < 0 || xx > 31) continue;
            acc += w[dy * 3 + dx] * img[yy * 32 + xx];
        }
    }
    return acc;
}

// ---------------------------------------------------------------------------
// lepe = dwconv3x3(q) + bias, fp32 [b][c][p].
// ---------------------------------------------------------------------------
__global__ void lepe_kernel(const float* __restrict__ q,
    const float* __restrict__ w, const float* __restrict__ b,
    float* __restrict__ lepe)
{
    int gid = blockIdx.x * 256 + threadIdx.x;     // 2^21
    int p = gid & 1023;
    int c = (gid >> 10) & 255;
    int yy = p >> 5, xx = p & 31;
    const float* img = q + (long)(gid - p);
    lepe[gid] = conv3(img, w + c * 9, yy, xx) + b[c];
}

// ---------------------------------------------------------------------------
// MFMA flash attention (T12 swapped-operand).  grid(16 mt, 64 bh), 4 waves.
// Per wave: 16 queries; S^T = mfma(K,Q) so each lane owns one query column;
// P^T B-frags for PV = mfma(V,P^T) come straight from S^T accum registers.
// Epilogue fuses +lepe and writes bf16 aoutT[b][p][c].
// ---------------------------------------------------------------------------
__global__ __launch_bounds__(256) void attn_mfma(
    const short* __restrict__ qT, const short* __restrict__ kT,
    const short* __restrict__ vN, const float* __restrict__ lep,
    short* __restrict__ aoutT)
{
    __shared__ short qS[64 * 32];
    __shared__ short kS[64 * 32];
    __shared__ short vS[32 * 64];
    __shared__ float oT[64 * 33];
    const int t = threadIdx.x;
    const int mt = blockIdx.x, bh = blockIdx.y;
    const int m0 = mt * 64;
    const int lane = t & 63, w = t >> 6;
    const int l15 = lane & 15, g = lane >> 4;
    const long base32 = (long)bh * 32768;          // bh*1024*32 == bh*32*1024
    f32x4 z = {0.f, 0.f, 0.f, 0.f};

    // stage Q tile (64 x 32)
    {
        int row = t >> 2, h = t & 3;
        bf16x8 v8 = *(const bf16x8*)(qT + base32 + (long)(m0 + row) * 32 + h * 8);
        stpair(qS, row, 32, h, (row >> 1) & 7, v8);
    }
    __syncthreads();
    const int qrow = w * 16 + l15;
    const bf16x8 qb = ldfrag(qS, qrow, 32, g, 4 + g, (qrow >> 1) & 7);

    float Mr = -1e30f, Lr = 0.f;
    f32x4 po[2]; po[0] = z; po[1] = z;

    for (int nt = 0; nt < 16; ++nt) {
        const int n0 = nt * 64;
        __syncthreads();
        {   // stage K^T tile (64n x 32c) and V tile (32c x 64n)
            int row = t >> 2, h = t & 3;
            bf16x8 v8 = *(const bf16x8*)(kT + base32 + (long)(n0 + row) * 32 + h * 8);
            stpair(kS, row, 32, h, (row >> 1) & 7, v8);
            int c = t >> 3, h2 = t & 7;
            bf16x8 u8 = *(const bf16x8*)(vN + base32 + (long)c * NPOS + n0 + h2 * 8);
            stpair(vS, c, 64, h2, c & 15, u8);
        }
        __syncthreads();
        // S^T: 4 frags (16n each), K=32 in one mfma
        f32x4 s[4];
        #pragma unroll
        for (int j = 0; j < 4; ++j) {
            int krow = j * 16 + l15;
            bf16x8 ka = ldfrag(kS, krow, 32, g, 4 + g, (krow >> 1) & 7);
            s[j] = __builtin_amdgcn_mfma_f32_16x16x32_bf16(ka, qb, z, 0, 0, 0);
        }
        // online softmax: lane owns query m = w*16+l15; partners at lane^16, ^32
        float mx = -1e30f;
        #pragma unroll
        for (int j = 0; j < 4; ++j)
            #pragma unroll
            for (int r = 0; r < 4; ++r) mx = fmaxf(mx, s[j][r]);
        mx = fmaxf(mx, __shfl_xor(mx, 16));
        mx = fmaxf(mx, __shfl_xor(mx, 32));
        float Mn = fmaxf(Mr, mx);
        float esc = __expf(Mr - Mn);
        Mr = Mn;
        float ls = 0.f;
        #pragma unroll
        for (int j = 0; j < 4; ++j)
            #pragma unroll
            for (int r = 0; r < 4; ++r) { s[j][r] = __expf(s[j][r] - Mn); ls += s[j][r]; }
        ls += __shfl_xor(ls, 16);
        ls += __shfl_xor(ls, 32);
        Lr = Lr * esc + ls;
        po[0] *= esc; po[1] *= esc;
        // P^T B-frags straight from S^T registers
        bf16x8 pb[2];
        #pragma unroll
        for (int ks = 0; ks < 2; ++ks)
            #pragma unroll
            for (int e = 0; e < 4; ++e) {
                pb[ks][e]     = f2bf(s[2 * ks][e]);
                pb[ks][4 + e] = f2bf(s[2 * ks + 1][e]);
            }
        // PV: O^T[c][m] += V[c][n] * P^T[n][m]
        #pragma unroll
        for (int cs = 0; cs < 2; ++cs) {
            int vrow = cs * 16 + l15;
            #pragma unroll
            for (int ks = 0; ks < 2; ++ks) {
                bf16x8 va = ldfrag(vS, vrow, 64, ks * 8 + g, ks * 8 + 4 + g, vrow & 15);
                po[cs] = __builtin_amdgcn_mfma_f32_16x16x32_bf16(va, pb[ks], po[cs], 0, 0, 0);
            }
        }
    }
    // epilogue: oT[m][c] then fused +lepe -> bf16 aoutT[b][p][c]
    float inv = 1.f / Lr;
    #pragma unroll
    for (int cs = 0; cs < 2; ++cs)
        #pragma unroll
        for (int r = 0; r < 4; ++r)
            oT[(w * 16 + l15) * 33 + cs * 16 + g * 4 + r] = po[cs][r] * inv;
    __syncthreads();
    #pragma unroll
    for (int i = 0; i < 8; ++i) {
        int idx = t + i * 256;
        int c = idx & 31, m = idx >> 5;
        float v = oT[m * 33 + c] + lep[base32 + (long)c * NPOS + m0 + m];
        aoutT[(((long)(bh >> 3)) * 1024 + m0 + m) * 256 + (bh & 7) * 32 + c] = f2bf(v);
    }
}

// ---------------------------------------------------------------------------
extern "C" void kernel_launch(void* const* d_in, const int* in_sizes, int n_in,
                              void* d_out, int out_size, void* d_ws, size_t ws_size,
                              hipStream_t stream)
{
    const float* x   = (const float*)d_in[0];
    const float* Wq  = (const float*)d_in[1];
    const float* bq  = (const float*)d_in[2];
    const float* Wk  = (const float*)d_in[3];
    const float* bk  = (const float*)d_in[4];
    const float* Wv  = (const float*)d_in[5];
    const float* bv  = (const float*)d_in[6];
    const float* Wo  = (const float*)d_in[7];
    const float* bo  = (const float*)d_in[8];
    const float* odw = (const float*)d_in[9];
    const float* odb = (const float*)d_in[10];
    const float* olg = (const float*)d_in[11];
    const float* olb = (const float*)d_in[12];
    const float* opw = (const float*)d_in[13];
    const float* rdw = (const float*)d_in[14];
    const float* rdb = (const float*)d_in[15];

    float* ws = (float*)d_ws;
    const size_t SZ = (size_t)2097152;            // 2M elements per big buffer
    float* qf  = ws;                              // fp32 q  [8][256][1024]
    float* lep = ws + SZ;                         // fp32 lepe
    float* pos = ws + 2 * SZ;                     // 65536 floats
    short* sb  = (short*)(ws + 2 * SZ + 65536);   // bf16 region (16B aligned)
    short* Wb  = sb;                              // 4 x 65536
    short* xT  = Wb + 262144;                     // [8][1024][256]
    short* xsT = xT + SZ;                         // [8][1024][256]
    short* qTb = xsT + SZ;                        // [64][1024][32]
    short* kTb = qTb + SZ;                        // [64][1024][32]
    short* vNb = kTb + SZ;                        // [8][256][1024]
    short* aoT = xT;                              // alias: xT dead after q GEMM
    float* y   = (float*)d_out;

    dim3 gg(16, 4, 8);
    cvt_w<<<1024, 256, 0, stream>>>(Wq, Wk, Wv, Wo, Wb);
    transpose_x<<<gg, 256, 0, stream>>>(x, xT);
    gemm_mfma<0><<<gg, 256, 0, stream>>>(Wb,          xT,  bq, qf,      qTb, nullptr);
    offset_kernel<<<dim3(32, 32), 256, 0, stream>>>(qf, odw, odb, olg, olb, opw, pos);
    sample_kernel<<<8192, 256, 0, stream>>>(x, pos, xsT);
    gemm_mfma<1><<<gg, 256, 0, stream>>>(Wb + 65536,  xsT, bk, nullptr, kTb, nullptr);
    gemm_mfma<2><<<gg, 256, 0, stream>>>(Wb + 131072, xsT, bv, nullptr, nullptr, vNb);
    lepe_kernel<<<8192, 256, 0, stream>>>(qf, rdw, rdb, lep);
    attn_mfma<<<dim3(16, 64), 256, 0, stream>>>(qTb, kTb, vNb, lep, aoT);
    gemm_mfma<3><<<gg, 256, 0, stream>>>(Wb + 196608, aoT, bo, y, nullptr, nullptr);
}

// Round 4
// 108.148 us; speedup vs baseline: 4.2566x; 1.1692x over previous
//
#include <hip/hip_runtime.h>
#include <math.h>

// Bottleneck_49039936586369: deformable attention, bf16-MFMA version.
// B=8, C=256, H=W=32, heads=8 (HC=32), groups=4 (GC=64), n=1024.

#define NPOS 1024

typedef float f32x4   __attribute__((ext_vector_type(4)));
typedef short bf16x8  __attribute__((ext_vector_type(8)));
typedef short short4v __attribute__((ext_vector_type(4)));

__device__ __forceinline__ short f2bf(float f) {
    unsigned u = __float_as_uint(f);
    unsigned r = (u + 0x7FFFu + ((u >> 16) & 1u)) >> 16;   // RNE
    return (short)r;
}

// Load one MFMA operand fragment (two-half k mapping) from an LDS tile with
// row length KE shorts and per-row b64-slot XOR swizzle.
__device__ __forceinline__ bf16x8 ldfrag(const short* base, int row, int KE,
                                         int s0, int s1, int swz) {
    const short* r = base + row * KE;
    short4v lo = *(const short4v*)(r + ((s0 ^ swz) << 2));
    short4v hi = *(const short4v*)(r + ((s1 ^ swz) << 2));
    bf16x8 f = {lo[0], lo[1], lo[2], lo[3], hi[0], hi[1], hi[2], hi[3]};
    return f;
}

// Store 8 bf16 (global b128 payload = slots 2h,2h+1) into swizzled LDS tile.
__device__ __forceinline__ void stpair(short* base, int row, int KE, int h, int swz,
                                       bf16x8 v8) {
    short4v lo = {v8[0], v8[1], v8[2], v8[3]};
    short4v hi = {v8[4], v8[5], v8[6], v8[7]};
    *(short4v*)(base + row * KE + (((2 * h) ^ swz) << 2)) = lo;
    *(short4v*)(base + row * KE + (((2 * h + 1) ^ swz) << 2)) = hi;
}

// ---------------------------------------------------------------------------
// Cast the four 256x256 weight matrices to bf16 (contiguous: q,k,v,o).
// ---------------------------------------------------------------------------
__global__ void cvt_w(const float* __restrict__ Wq, const float* __restrict__ Wk,
                      const float* __restrict__ Wv, const float* __restrict__ Wo,
                      short* __restrict__ Wb)
{
    int gid = blockIdx.x * 256 + threadIdx.x;      // 262144
    const float* src = (gid < 65536) ? Wq : (gid < 131072) ? Wk
                     : (gid < 196608) ? Wv : Wo;
    Wb[gid] = f2bf(src[gid & 65535]);
}

// ---------------------------------------------------------------------------
// xT[b][p][c] bf16  <-  x[b][c][p] fp32.  grid(16,4,8), 64x64 tiles.
// ---------------------------------------------------------------------------
__global__ __launch_bounds__(256) void transpose_x(const float* __restrict__ x,
                                                   short* __restrict__ xT)
{
    __shared__ float tile[64][69];
    const int p0 = blockIdx.x * 64, c0 = blockIdx.y * 64, b = blockIdx.z;
    const int t = threadIdx.x;
    #pragma unroll
    for (int i = 0; i < 4; ++i) {
        int id = t + i * 256;              // 64 rows x 16 float4
        int row = id >> 4, q = id & 15;
        float4 v = *(const float4*)(x + ((long)(b * 256 + c0 + row)) * NPOS + p0 + q * 4);
        tile[row][q * 4 + 0] = v.x; tile[row][q * 4 + 1] = v.y;
        tile[row][q * 4 + 2] = v.z; tile[row][q * 4 + 3] = v.w;
    }
    __syncthreads();
    #pragma unroll
    for (int i = 0; i < 2; ++i) {
        int id = t + i * 256;              // 64 p x 8 cgroups
        int p = id >> 3, cg = id & 7;
        bf16x8 o;
        #pragma unroll
        for (int j = 0; j < 8; ++j) o[j] = f2bf(tile[cg * 8 + j][p]);
        *(bf16x8*)(xT + ((long)(b * 1024 + p0 + p)) * 256 + c0 + cg * 8) = o;
    }
}

// ---------------------------------------------------------------------------
// bf16 MFMA GEMM: Y[b] = W(256x256) @ X[b](256x1024) + bias.
// A = Wb [m][k] bf16;  B = Xt [b][n][k] bf16 (n-major).  grid(16,4,8), 4 waves.
// MODE 0: fp32 q natural + bf16 qT[bh][n][hc] (scaled);  3: fp32 y natural.
// ---------------------------------------------------------------------------
template<int MODE>
__global__ __launch_bounds__(256) void gemm_mfma(
    const short* __restrict__ A, const short* __restrict__ Bt,
    const float* __restrict__ bias,
    float* __restrict__ outF, short* __restrict__ outT)
{
    __shared__ short As[64 * 64];
    __shared__ short Bs[64 * 64];
    const int t = threadIdx.x;
    const int n0 = blockIdx.x * 64, m0 = blockIdx.y * 64;
    const int b = blockIdx.z;
    const int lane = t & 63, w = t >> 6;
    const int wm = w >> 1, wn = w & 1;
    const int l15 = lane & 15, g = lane >> 4;
    f32x4 z = {0.f, 0.f, 0.f, 0.f};
    f32x4 acc[2][2];
    acc[0][0] = z; acc[0][1] = z; acc[1][0] = z; acc[1][1] = z;

    for (int kt = 0; kt < 4; ++kt) {
        const int k0 = kt * 64;
        __syncthreads();
        #pragma unroll
        for (int i = 0; i < 2; ++i) {
            int q = t + i * 256;           // 512 chunks per tile
            int row = q >> 3, p = q & 7;
            bf16x8 av = *(const bf16x8*)(A + (long)(m0 + row) * 256 + k0 + p * 8);
            stpair(As, row, 64, p, row & 15, av);
            bf16x8 bv = *(const bf16x8*)(Bt + ((long)b * 1024 + n0 + row) * 256 + k0 + p * 8);
            stpair(Bs, row, 64, p, row & 15, bv);
        }
        __syncthreads();
        #pragma unroll
        for (int kk = 0; kk < 2; ++kk) {
            bf16x8 af[2], bfr[2];
            #pragma unroll
            for (int mi = 0; mi < 2; ++mi) {
                int row = wm * 32 + mi * 16 + l15;
                af[mi] = ldfrag(As, row, 64, kk * 8 + g, kk * 8 + 4 + g, row & 15);
            }
            #pragma unroll
            for (int ni = 0; ni < 2; ++ni) {
                int row = wn * 32 + ni * 16 + l15;
                bfr[ni] = ldfrag(Bs, row, 64, kk * 8 + g, kk * 8 + 4 + g, row & 15);
            }
            #pragma unroll
            for (int mi = 0; mi < 2; ++mi)
                #pragma unroll
                for (int ni = 0; ni < 2; ++ni)
                    acc[mi][ni] = __builtin_amdgcn_mfma_f32_16x16x32_bf16(
                        af[mi], bfr[ni], acc[mi][ni], 0, 0, 0);
        }
    }
    // epilogue: m = m0+wm*32+mi*16+g*4+j, n = n0+wn*32+ni*16+l15
    #pragma unroll
    for (int mi = 0; mi < 2; ++mi) {
        const int mbase = m0 + wm * 32 + mi * 16 + g * 4;
        float bv[4];
        #pragma unroll
        for (int j = 0; j < 4; ++j) bv[j] = bias[mbase + j];
        #pragma unroll
        for (int ni = 0; ni < 2; ++ni) {
            const int n = n0 + wn * 32 + ni * 16 + l15;
            f32x4 r = acc[mi][ni];
            #pragma unroll
            for (int j = 0; j < 4; ++j) r[j] += bv[j];
            #pragma unroll
            for (int j = 0; j < 4; ++j)
                outF[((long)b * 256 + mbase + j) * NPOS + n] = r[j];
            if constexpr (MODE == 0) {
                const float sc = 0.17677669529663687f;   // HC^-0.5
                short4v p = {f2bf(r[0] * sc), f2bf(r[1] * sc),
                             f2bf(r[2] * sc), f2bf(r[3] * sc)};
                int bh = b * 8 + (mbase >> 5);
                *(short4v*)(outT + ((long)bh * 1024 + n) * 32 + (mbase & 31)) = p;
            }
        }
    }
}

// ---------------------------------------------------------------------------
// Fused K+V GEMM: stages the xsT B-tile once, runs both Wk and Wv A-tiles.
// Outputs kT[bh][n][32] bf16 (natural-scale) and vN[b][c][n] bf16.
// ---------------------------------------------------------------------------
__global__ __launch_bounds__(256) void gemm_kv(
    const short* __restrict__ Ak, const short* __restrict__ Av,
    const short* __restrict__ Bt,
    const float* __restrict__ bk, const float* __restrict__ bv,
    short* __restrict__ kT, short* __restrict__ vN)
{
    __shared__ short Ks[64 * 64];
    __shared__ short Vs[64 * 64];
    __shared__ short Bs[64 * 64];
    const int t = threadIdx.x;
    const int n0 = blockIdx.x * 64, m0 = blockIdx.y * 64;
    const int b = blockIdx.z;
    const int lane = t & 63, w = t >> 6;
    const int wm = w >> 1, wn = w & 1;
    const int l15 = lane & 15, g = lane >> 4;
    f32x4 z = {0.f, 0.f, 0.f, 0.f};
    f32x4 acck[2][2], accv[2][2];
    acck[0][0] = z; acck[0][1] = z; acck[1][0] = z; acck[1][1] = z;
    accv[0][0] = z; accv[0][1] = z; accv[1][0] = z; accv[1][1] = z;

    for (int kt = 0; kt < 4; ++kt) {
        const int k0 = kt * 64;
        __syncthreads();
        #pragma unroll
        for (int i = 0; i < 2; ++i) {
            int q = t + i * 256;
            int row = q >> 3, p = q & 7;
            bf16x8 a1 = *(const bf16x8*)(Ak + (long)(m0 + row) * 256 + k0 + p * 8);
            stpair(Ks, row, 64, p, row & 15, a1);
            bf16x8 a2 = *(const bf16x8*)(Av + (long)(m0 + row) * 256 + k0 + p * 8);
            stpair(Vs, row, 64, p, row & 15, a2);
            bf16x8 bb = *(const bf16x8*)(Bt + ((long)b * 1024 + n0 + row) * 256 + k0 + p * 8);
            stpair(Bs, row, 64, p, row & 15, bb);
        }
        __syncthreads();
        #pragma unroll
        for (int kk = 0; kk < 2; ++kk) {
            bf16x8 afk[2], afv[2], bfr[2];
            #pragma unroll
            for (int mi = 0; mi < 2; ++mi) {
                int row = wm * 32 + mi * 16 + l15;
                afk[mi] = ldfrag(Ks, row, 64, kk * 8 + g, kk * 8 + 4 + g, row & 15);
                afv[mi] = ldfrag(Vs, row, 64, kk * 8 + g, kk * 8 + 4 + g, row & 15);
            }
            #pragma unroll
            for (int ni = 0; ni < 2; ++ni) {
                int row = wn * 32 + ni * 16 + l15;
                bfr[ni] = ldfrag(Bs, row, 64, kk * 8 + g, kk * 8 + 4 + g, row & 15);
            }
            #pragma unroll
            for (int mi = 0; mi < 2; ++mi)
                #pragma unroll
                for (int ni = 0; ni < 2; ++ni) {
                    acck[mi][ni] = __builtin_amdgcn_mfma_f32_16x16x32_bf16(
                        afk[mi], bfr[ni], acck[mi][ni], 0, 0, 0);
                    accv[mi][ni] = __builtin_amdgcn_mfma_f32_16x16x32_bf16(
                        afv[mi], bfr[ni], accv[mi][ni], 0, 0, 0);
                }
        }
    }
    #pragma unroll
    for (int mi = 0; mi < 2; ++mi) {
        const int mbase = m0 + wm * 32 + mi * 16 + g * 4;
        float bk4[4], bv4[4];
        #pragma unroll
        for (int j = 0; j < 4; ++j) { bk4[j] = bk[mbase + j]; bv4[j] = bv[mbase + j]; }
        #pragma unroll
        for (int ni = 0; ni < 2; ++ni) {
            const int n = n0 + wn * 32 + ni * 16 + l15;
            f32x4 rk = acck[mi][ni], rv = accv[mi][ni];
            // k -> kT[bh][n][32]
            short4v pk = {f2bf(rk[0] + bk4[0]), f2bf(rk[1] + bk4[1]),
                          f2bf(rk[2] + bk4[2]), f2bf(rk[3] + bk4[3])};
            int bh = b * 8 + (mbase >> 5);
            *(short4v*)(kT + ((long)bh * 1024 + n) * 32 + (mbase & 31)) = pk;
            // v -> vN[b][c][n]
            #pragma unroll
            for (int j = 0; j < 4; ++j)
                vN[((long)b * 256 + mbase + j) * NPOS + n] = f2bf(rv[j] + bv4[j]);
        }
    }
}

// ---------------------------------------------------------------------------
// Offset branch, cooperative: one block per (bg, image row y).
// ---------------------------------------------------------------------------
__global__ __launch_bounds__(256) void offset_kernel(const float* __restrict__ q,
    const float* __restrict__ dww, const float* __restrict__ dwb,
    const float* __restrict__ lng, const float* __restrict__ lnb,
    const float* __restrict__ pww, float* __restrict__ pos)
{
    __shared__ float q3[64][3][33];   // [c][row][x]
    __shared__ float wS[576];
    __shared__ float bS[64], gS[64], lbS[64], pS[128];
    const int t = threadIdx.x;
    const int y = blockIdx.x, bg = blockIdx.y;
    const float* qb = q + (long)bg * 64 * NPOS;
    for (int i = t; i < 576; i += 256) wS[i] = dww[i];
    if (t < 64) { bS[t] = dwb[t]; gS[t] = lng[t]; lbS[t] = lnb[t]; }
    else if (t >= 128 && t < 256) pS[t - 128] = pww[t - 128];
    #pragma unroll
    for (int i = 0; i < 6; ++i) {
        int id = t + i * 256;                 // 0..1535 = 64c x 3r x 8 float4
        int c = id / 24, rx = id - c * 24;
        int r = rx >> 3, q4 = (rx & 7) * 4;
        int yy = y + r - 1;
        float4 v = make_float4(0.f, 0.f, 0.f, 0.f);
        if (yy >= 0 && yy < 32)
            v = *(const float4*)(qb + (long)c * NPOS + yy * 32 + q4);
        q3[c][r][q4 + 0] = v.x; q3[c][r][q4 + 1] = v.y;
        q3[c][r][q4 + 2] = v.z; q3[c][r][q4 + 3] = v.w;
    }
    __syncthreads();
    const int p = t >> 3, cg = t & 7;
    float oc[8];
    float s = 0.f, s2 = 0.f;
    #pragma unroll
    for (int j = 0; j < 8; ++j) {
        int c = cg * 8 + j;
        float acc = bS[c];
        #pragma unroll
        for (int dy = 0; dy < 3; ++dy)
            #pragma unroll
            for (int dx = 0; dx < 3; ++dx) {
                int xx = p + dx - 1;
                if (xx >= 0 && xx < 32)
                    acc += wS[c * 9 + dy * 3 + dx] * q3[c][dy][xx];
            }
        oc[j] = acc;
        s += acc; s2 += acc * acc;
    }
    s  += __shfl_xor(s, 1);  s  += __shfl_xor(s, 2);  s  += __shfl_xor(s, 4);
    s2 += __shfl_xor(s2, 1); s2 += __shfl_xor(s2, 2); s2 += __shfl_xor(s2, 4);
    float mu = s * 0.015625f;
    float var = s2 * 0.015625f - mu * mu;
    float rstd = rsqrtf(var + 1e-5f);
    float a0 = 0.f, a1 = 0.f;
    #pragma unroll
    for (int j = 0; j < 8; ++j) {
        int c = cg * 8 + j;
        float on = (oc[j] - mu) * rstd * gS[c] + lbS[c];
        float ge = 0.5f * on * (1.f + erff(on * 0.70710678118654752f));
        a0 += pS[c] * ge;
        a1 += pS[64 + c] * ge;
    }
    a0 += __shfl_xor(a0, 1); a0 += __shfl_xor(a0, 2); a0 += __shfl_xor(a0, 4);
    a1 += __shfl_xor(a1, 1); a1 += __shfl_xor(a1, 2); a1 += __shfl_xor(a1, 4);
    if (cg == 0) {
        const float rng = 4.f / 31.f;
        float offy = tanhf(a0) * rng;
        float offx = tanhf(a1) * rng;
        float ry = ((y + 0.5f) / 31.f) * 2.f - 1.f;
        float rx = ((p + 0.5f) / 31.f) * 2.f - 1.f;
        int pp = y * 32 + p;
        pos[(long)bg * 2048 + pp * 2 + 0] = offy + ry;
        pos[(long)bg * 2048 + pp * 2 + 1] = offx + rx;
    }
}

// ---------------------------------------------------------------------------
// Bilinear grid-sample -> bf16 xsT[b][p][c] (c fastest for coalesced writes).
// ---------------------------------------------------------------------------
__global__ void sample_kernel(const float* __restrict__ x,
    const float* __restrict__ pos, short* __restrict__ xsT)
{
    int gid = blockIdx.x * 256 + threadIdx.x;     // 2^21
    int cc = gid & 63;
    int p  = (gid >> 6) & 1023;
    int bg = gid >> 16;
    float py = pos[(long)bg * 2048 + p * 2 + 0];
    float px = pos[(long)bg * 2048 + p * 2 + 1];
    float fy = (py + 1.f) * 15.5f;
    float fx = (px + 1.f) * 15.5f;
    float y0f = floorf(fy), x0f = floorf(fx);
    int y0 = (int)y0f, x0 = (int)x0f;
    float yw = fy - y0f, xw = fx - x0f;
    const float* img = x + ((long)bg * 64 + cc) * NPOS;
    float acc = 0.f;
    { int yi = y0,     xi = x0;     float wg = (1.f - yw) * (1.f - xw);
      if (yi >= 0 && yi < 32 && xi >= 0 && xi < 32) acc += wg * img[yi * 32 + xi]; }
    { int yi = y0,     xi = x0 + 1; float wg = (1.f - yw) * xw;
      if (yi >= 0 && yi < 32 && xi >= 0 && xi < 32) acc += wg * img[yi * 32 + xi]; }
    { int yi = y0 + 1, xi = x0;     float wg = yw * (1.f - xw);
      if (yi >= 0 && yi < 32 && xi >= 0 && xi < 32) acc += wg * img[yi * 32 + xi]; }
    { int yi = y0 + 1, xi = x0 + 1; float wg = yw * xw;
      if (yi >= 0 && yi < 32 && xi >= 0 && xi < 32) acc += wg * img[yi * 32 + xi]; }
    xsT[((long)(bg >> 2) * 1024 + p) * 256 + (bg & 3) * 64 + cc] = f2bf(acc);
}

// ---------------------------------------------------------------------------
// MFMA flash attention (T12 swapped-operand) with FUSED lepe dwconv.
// grid(16 mt, 64 bh), 4 waves.  Block covers image rows {2mt, 2mt+1} x 32 ch
// of head bh -> lepe needs q rows 2mt-1..2mt+2 x 32 ch, staged once at start.
// Epilogue: out = O/L + dwconv3x3(q) + rpe_bias, written bf16 aoutT[b][p][c].
// ---------------------------------------------------------------------------
__global__ __launch_bounds__(256) void attn_mfma(
    const short* __restrict__ qT, const short* __restrict__ kT,
    const short* __restrict__ vN, const float* __restrict__ qf,
    const float* __restrict__ rdw, const float* __restrict__ rdb,
    short* __restrict__ aoutT)
{
    __shared__ short qS[64 * 32];
    __shared__ short kS[64 * 32];
    __shared__ short vS[32 * 64];
    __shared__ float oT[64 * 33];
    __shared__ float qr[4][32][33];   // [row][cc][x] q rows for lepe conv
    __shared__ float wR[288], bR[32];
    const int t = threadIdx.x;
    const int mt = blockIdx.x, bh = blockIdx.y;
    const int m0 = mt * 64;
    const int lane = t & 63, w = t >> 6;
    const int l15 = lane & 15, g = lane >> 4;
    const long base32 = (long)bh * 32768;          // bh*1024*32 == bh*32*1024
    const int c0 = (bh & 7) * 32;                  // global channel base
    f32x4 z = {0.f, 0.f, 0.f, 0.f};

    // stage Q tile (64 x 32)
    {
        int row = t >> 2, h = t & 3;
        bf16x8 v8 = *(const bf16x8*)(qT + base32 + (long)(m0 + row) * 32 + h * 8);
        stpair(qS, row, 32, h, (row >> 1) & 7, v8);
    }
    // stage q rows 2mt-1 .. 2mt+2 (zero-padded) for lepe conv + rpe weights
    {
        const int y0 = (m0 >> 5) - 1;
        #pragma unroll
        for (int i = 0; i < 4; ++i) {
            int id = t + i * 256;              // r(2) cc(5) xq(3)
            int xq = id & 7, cc = (id >> 3) & 31, r = id >> 8;
            int yy = y0 + r;
            float4 v = make_float4(0.f, 0.f, 0.f, 0.f);
            if (yy >= 0 && yy < 32)
                v = *(const float4*)(qf + base32 + (long)cc * NPOS + yy * 32 + xq * 4);
            qr[r][cc][xq * 4 + 0] = v.x; qr[r][cc][xq * 4 + 1] = v.y;
            qr[r][cc][xq * 4 + 2] = v.z; qr[r][cc][xq * 4 + 3] = v.w;
        }
        if (t < 32) bR[t] = rdb[c0 + t];
        for (int i = t; i < 288; i += 256) wR[i] = rdw[c0 * 9 + i];
    }
    __syncthreads();
    const int qrow = w * 16 + l15;
    const bf16x8 qb = ldfrag(qS, qrow, 32, g, 4 + g, (qrow >> 1) & 7);

    float Mr = -1e30f, Lr = 0.f;
    f32x4 po[2]; po[0] = z; po[1] = z;

    for (int nt = 0; nt < 16; ++nt) {
        const int n0 = nt * 64;
        __syncthreads();
        {   // stage K^T tile (64n x 32c) and V tile (32c x 64n)
            int row = t >> 2, h = t & 3;
            bf16x8 v8 = *(const bf16x8*)(kT + base32 + (long)(n0 + row) * 32 + h * 8);
            stpair(kS, row, 32, h, (row >> 1) & 7, v8);
            int c = t >> 3, h2 = t & 7;
            bf16x8 u8 = *(const bf16x8*)(vN + base32 + (long)c * NPOS + n0 + h2 * 8);
            stpair(vS, c, 64, h2, c & 15, u8);
        }
        __syncthreads();
        // S^T: 4 frags (16n each), K=32 in one mfma
        f32x4 s[4];
        #pragma unroll
        for (int j = 0; j < 4; ++j) {
            int krow = j * 16 + l15;
            bf16x8 ka = ldfrag(kS, krow, 32, g, 4 + g, (krow >> 1) & 7);
            s[j] = __builtin_amdgcn_mfma_f32_16x16x32_bf16(ka, qb, z, 0, 0, 0);
        }
        // online softmax: lane owns query m = w*16+l15; partners at lane^16, ^32
        float mx = -1e30f;
        #pragma unroll
        for (int j = 0; j < 4; ++j)
            #pragma unroll
            for (int r = 0; r < 4; ++r) mx = fmaxf(mx, s[j][r]);
        mx = fmaxf(mx, __shfl_xor(mx, 16));
        mx = fmaxf(mx, __shfl_xor(mx, 32));
        float Mn = fmaxf(Mr, mx);
        float esc = __expf(Mr - Mn);
        Mr = Mn;
        float ls = 0.f;
        #pragma unroll
        for (int j = 0; j < 4; ++j)
            #pragma unroll
            for (int r = 0; r < 4; ++r) { s[j][r] = __expf(s[j][r] - Mn); ls += s[j][r]; }
        ls += __shfl_xor(ls, 16);
        ls += __shfl_xor(ls, 32);
        Lr = Lr * esc + ls;
        po[0] *= esc; po[1] *= esc;
        // P^T B-frags straight from S^T registers
        bf16x8 pb[2];
        #pragma unroll
        for (int ks = 0; ks < 2; ++ks)
            #pragma unroll
            for (int e = 0; e < 4; ++e) {
                pb[ks][e]     = f2bf(s[2 * ks][e]);
                pb[ks][4 + e] = f2bf(s[2 * ks + 1][e]);
            }
        // PV: O^T[c][m] += V[c][n] * P^T[n][m]
        #pragma unroll
        for (int cs = 0; cs < 2; ++cs) {
            int vrow = cs * 16 + l15;
            #pragma unroll
            for (int ks = 0; ks < 2; ++ks) {
                bf16x8 va = ldfrag(vS, vrow, 64, ks * 8 + g, ks * 8 + 4 + g, vrow & 15);
                po[cs] = __builtin_amdgcn_mfma_f32_16x16x32_bf16(va, pb[ks], po[cs], 0, 0, 0);
            }
        }
    }
    // epilogue: oT[m][c], then + lepe conv from qr, write bf16 aoutT[b][p][c]
    float inv = 1.f / Lr;
    #pragma unroll
    for (int cs = 0; cs < 2; ++cs)
        #pragma unroll
        for (int r = 0; r < 4; ++r)
            oT[(w * 16 + l15) * 33 + cs * 16 + g * 4 + r] = po[cs][r] * inv;
    __syncthreads();
    #pragma unroll
    for (int i = 0; i < 8; ++i) {
        int idx = t + i * 256;
        int c = idx & 31, m = idx >> 5;
        int ml = m >> 5, xx0 = m & 31;        // local row, x
        float acc = 0.f;
        #pragma unroll
        for (int dy = 0; dy < 3; ++dy)
            #pragma unroll
            for (int dx = 0; dx < 3; ++dx) {
                int xx = xx0 + dx - 1;
                if (xx >= 0 && xx < 32)
                    acc += wR[c * 9 + dy * 3 + dx] * qr[ml + dy][c][xx];
            }
        float v = oT[m * 33 + c] + acc + bR[c];
        aoutT[(((long)(bh >> 3)) * 1024 + m0 + m) * 256 + (bh & 7) * 32 + c] = f2bf(v);
    }
}

// ---------------------------------------------------------------------------
extern "C" void kernel_launch(void* const* d_in, const int* in_sizes, int n_in,
                              void* d_out, int out_size, void* d_ws, size_t ws_size,
                              hipStream_t stream)
{
    const float* x   = (const float*)d_in[0];
    const float* Wq  = (const float*)d_in[1];
    const float* bq  = (const float*)d_in[2];
    const float* Wk  = (const float*)d_in[3];
    const float* bk  = (const float*)d_in[4];
    const float* Wv  = (const float*)d_in[5];
    const float* bv  = (const float*)d_in[6];
    const float* Wo  = (const float*)d_in[7];
    const float* bo  = (const float*)d_in[8];
    const float* odw = (const float*)d_in[9];
    const float* odb = (const float*)d_in[10];
    const float* olg = (const float*)d_in[11];
    const float* olb = (const float*)d_in[12];
    const float* opw = (const float*)d_in[13];
    const float* rdw = (const float*)d_in[14];
    const float* rdb = (const float*)d_in[15];

    float* ws = (float*)d_ws;
    const size_t SZ = (size_t)2097152;            // 2M elements per big buffer
    float* qf  = ws;                              // fp32 q  [8][256][1024]
    float* pos = ws + SZ;                         // 65536 floats
    short* sb  = (short*)(ws + SZ + 65536);       // bf16 region (16B aligned)
    short* Wb  = sb;                              // 4 x 65536
    short* xT  = Wb + 262144;                     // [8][1024][256]
    short* xsT = xT + SZ;                         // [8][1024][256]
    short* qTb = xsT + SZ;                        // [64][1024][32]
    short* kTb = qTb + SZ;                        // [64][1024][32]
    short* vNb = kTb + SZ;                        // [8][256][1024]
    short* aoT = xT;                              // alias: xT dead after q GEMM
    float* y   = (float*)d_out;

    dim3 gg(16, 4, 8);
    cvt_w<<<1024, 256, 0, stream>>>(Wq, Wk, Wv, Wo, Wb);
    transpose_x<<<gg, 256, 0, stream>>>(x, xT);
    gemm_mfma<0><<<gg, 256, 0, stream>>>(Wb, xT, bq, qf, qTb);
    offset_kernel<<<dim3(32, 32), 256, 0, stream>>>(qf, odw, odb, olg, olb, opw, pos);
    sample_kernel<<<8192, 256, 0, stream>>>(x, pos, xsT);
    gemm_kv<<<gg, 256, 0, stream>>>(Wb + 65536, Wb + 131072, xsT, bk, bv, kTb, vNb);
    attn_mfma<<<dim3(16, 64), 256, 0, stream>>>(qTb, kTb, vNb, qf, rdw, rdb, aoT);
    gemm_mfma<3><<<gg, 256, 0, stream>>>(Wb + 196608, aoT, bo, y, nullptr);
}

// Round 5
// 106.637 us; speedup vs baseline: 4.3169x; 1.0142x over previous
//
#include <hip/hip_runtime.h>
#include <math.h>

// Bottleneck_49039936586369: deformable attention, bf16-MFMA version.
// B=8, C=256, H=W=32, heads=8 (HC=32), groups=4 (GC=64), n=1024.

#define NPOS 1024

typedef float f32x4   __attribute__((ext_vector_type(4)));
typedef short bf16x8  __attribute__((ext_vector_type(8)));
typedef short short4v __attribute__((ext_vector_type(4)));
typedef unsigned uint4v __attribute__((ext_vector_type(4)));

__device__ __forceinline__ short f2bf(float f) {
    unsigned u = __float_as_uint(f);
    unsigned r = (u + 0x7FFFu + ((u >> 16) & 1u)) >> 16;   // RNE
    return (short)r;
}
__device__ __forceinline__ float bf2f(short s) {
    return __uint_as_float(((unsigned)(unsigned short)s) << 16);
}
// pack two f32 -> two bf16 in one reg (no builtin on gfx950; T12 recipe)
__device__ __forceinline__ unsigned cvtpk(float a, float b) {
    unsigned r;
    asm("v_cvt_pk_bf16_f32 %0, %1, %2" : "=v"(r) : "v"(a), "v"(b));
    return r;
}

// Load one MFMA operand fragment (two-half k mapping) from an LDS tile with
// row length KE shorts and per-row b64-slot XOR swizzle.
__device__ __forceinline__ bf16x8 ldfrag(const short* base, int row, int KE,
                                         int s0, int s1, int swz) {
    const short* r = base + row * KE;
    short4v lo = *(const short4v*)(r + ((s0 ^ swz) << 2));
    short4v hi = *(const short4v*)(r + ((s1 ^ swz) << 2));
    bf16x8 f = {lo[0], lo[1], lo[2], lo[3], hi[0], hi[1], hi[2], hi[3]};
    return f;
}

// Store 8 bf16 (global b128 payload = slots 2h,2h+1) into swizzled LDS tile.
__device__ __forceinline__ void stpair(short* base, int row, int KE, int h, int swz,
                                       bf16x8 v8) {
    short4v lo = {v8[0], v8[1], v8[2], v8[3]};
    short4v hi = {v8[4], v8[5], v8[6], v8[7]};
    *(short4v*)(base + row * KE + (((2 * h) ^ swz) << 2)) = lo;
    *(short4v*)(base + row * KE + (((2 * h + 1) ^ swz) << 2)) = hi;
}

// ---------------------------------------------------------------------------
// Cast the four 256x256 weight matrices to bf16 (contiguous: q,k,v,o).
// ---------------------------------------------------------------------------
__global__ void cvt_w(const float* __restrict__ Wq, const float* __restrict__ Wk,
                      const float* __restrict__ Wv, const float* __restrict__ Wo,
                      short* __restrict__ Wb)
{
    int gid = blockIdx.x * 256 + threadIdx.x;      // 262144
    const float* src = (gid < 65536) ? Wq : (gid < 131072) ? Wk
                     : (gid < 196608) ? Wv : Wo;
    Wb[gid] = f2bf(src[gid & 65535]);
}

// ---------------------------------------------------------------------------
// xT[b][p][c] bf16  <-  x[b][c][p] fp32.  grid(16,4,8), 64x64 tiles.
// ---------------------------------------------------------------------------
__global__ __launch_bounds__(256) void transpose_x(const float* __restrict__ x,
                                                   short* __restrict__ xT)
{
    __shared__ float tile[64][69];
    const int p0 = blockIdx.x * 64, c0 = blockIdx.y * 64, b = blockIdx.z;
    const int t = threadIdx.x;
    #pragma unroll
    for (int i = 0; i < 4; ++i) {
        int id = t + i * 256;              // 64 rows x 16 float4
        int row = id >> 4, q = id & 15;
        float4 v = *(const float4*)(x + ((long)(b * 256 + c0 + row)) * NPOS + p0 + q * 4);
        tile[row][q * 4 + 0] = v.x; tile[row][q * 4 + 1] = v.y;
        tile[row][q * 4 + 2] = v.z; tile[row][q * 4 + 3] = v.w;
    }
    __syncthreads();
    #pragma unroll
    for (int i = 0; i < 2; ++i) {
        int id = t + i * 256;              // 64 p x 8 cgroups
        int p = id >> 3, cg = id & 7;
        bf16x8 o;
        #pragma unroll
        for (int j = 0; j < 8; ++j) o[j] = f2bf(tile[cg * 8 + j][p]);
        *(bf16x8*)(xT + ((long)(b * 1024 + p0 + p)) * 256 + c0 + cg * 8) = o;
    }
}

// ---------------------------------------------------------------------------
// bf16 MFMA GEMM: Y[b] = W(256x256) @ X[b](256x1024) + bias.
// 2-phase double-buffered LDS (reg prefetch, one barrier per K-step).
// MODE 0: fp32 q natural + bf16 qT[bh][n][hc] (scaled by HC^-0.5 * log2e);
// MODE 3: fp32 y natural.
// ---------------------------------------------------------------------------
template<int MODE>
__global__ __launch_bounds__(256) void gemm_mfma(
    const short* __restrict__ A, const short* __restrict__ Bt,
    const float* __restrict__ bias,
    float* __restrict__ outF, short* __restrict__ outT)
{
    __shared__ short As[2][64 * 64];
    __shared__ short Bs[2][64 * 64];
    const int t = threadIdx.x;
    const int n0 = blockIdx.x * 64, m0 = blockIdx.y * 64;
    const int b = blockIdx.z;
    const int lane = t & 63, w = t >> 6;
    const int wm = w >> 1, wn = w & 1;
    const int l15 = lane & 15, g = lane >> 4;
    const int srow = t >> 3, sp = t & 7;
    f32x4 z = {0.f, 0.f, 0.f, 0.f};
    f32x4 acc[2][2];
    acc[0][0] = z; acc[0][1] = z; acc[1][0] = z; acc[1][1] = z;

    bf16x8 ar[2], br[2];
    #pragma unroll
    for (int i = 0; i < 2; ++i) {
        int row = srow + i * 32;
        ar[i] = *(const bf16x8*)(A + (long)(m0 + row) * 256 + sp * 8);
        br[i] = *(const bf16x8*)(Bt + ((long)b * 1024 + n0 + row) * 256 + sp * 8);
        stpair(As[0], row, 64, sp, row & 15, ar[i]);
        stpair(Bs[0], row, 64, sp, row & 15, br[i]);
    }
    __syncthreads();

    for (int kt = 0; kt < 4; ++kt) {
        const int cur = kt & 1;
        if (kt < 3) {
            const int k0 = (kt + 1) * 64;
            #pragma unroll
            for (int i = 0; i < 2; ++i) {
                int row = srow + i * 32;
                ar[i] = *(const bf16x8*)(A + (long)(m0 + row) * 256 + k0 + sp * 8);
                br[i] = *(const bf16x8*)(Bt + ((long)b * 1024 + n0 + row) * 256 + k0 + sp * 8);
            }
        }
        #pragma unroll
        for (int kk = 0; kk < 2; ++kk) {
            bf16x8 af[2], bfr[2];
            #pragma unroll
            for (int mi = 0; mi < 2; ++mi) {
                int row = wm * 32 + mi * 16 + l15;
                af[mi] = ldfrag(As[cur], row, 64, kk * 8 + g, kk * 8 + 4 + g, row & 15);
            }
            #pragma unroll
            for (int ni = 0; ni < 2; ++ni) {
                int row = wn * 32 + ni * 16 + l15;
                bfr[ni] = ldfrag(Bs[cur], row, 64, kk * 8 + g, kk * 8 + 4 + g, row & 15);
            }
            __builtin_amdgcn_s_setprio(1);
            #pragma unroll
            for (int mi = 0; mi < 2; ++mi)
                #pragma unroll
                for (int ni = 0; ni < 2; ++ni)
                    acc[mi][ni] = __builtin_amdgcn_mfma_f32_16x16x32_bf16(
                        af[mi], bfr[ni], acc[mi][ni], 0, 0, 0);
            __builtin_amdgcn_s_setprio(0);
        }
        if (kt < 3) {
            #pragma unroll
            for (int i = 0; i < 2; ++i) {
                int row = srow + i * 32;
                stpair(As[cur ^ 1], row, 64, sp, row & 15, ar[i]);
                stpair(Bs[cur ^ 1], row, 64, sp, row & 15, br[i]);
            }
        }
        __syncthreads();
    }
    // epilogue: m = m0+wm*32+mi*16+g*4+j, n = n0+wn*32+ni*16+l15
    #pragma unroll
    for (int mi = 0; mi < 2; ++mi) {
        const int mbase = m0 + wm * 32 + mi * 16 + g * 4;
        float bv[4];
        #pragma unroll
        for (int j = 0; j < 4; ++j) bv[j] = bias[mbase + j];
        #pragma unroll
        for (int ni = 0; ni < 2; ++ni) {
            const int n = n0 + wn * 32 + ni * 16 + l15;
            f32x4 r = acc[mi][ni];
            #pragma unroll
            for (int j = 0; j < 4; ++j) r[j] += bv[j];
            #pragma unroll
            for (int j = 0; j < 4; ++j)
                outF[((long)b * 256 + mbase + j) * NPOS + n] = r[j];
            if constexpr (MODE == 0) {
                const float sc = 0.25503486f;   // HC^-0.5 * log2(e)  (exp2 softmax)
                short4v p = {f2bf(r[0] * sc), f2bf(r[1] * sc),
                             f2bf(r[2] * sc), f2bf(r[3] * sc)};
                int bh = b * 8 + (mbase >> 5);
                *(short4v*)(outT + ((long)bh * 1024 + n) * 32 + (mbase & 31)) = p;
            }
        }
    }
}

// ---------------------------------------------------------------------------
// Fused K+V GEMM, 2-phase double-buffered.  kT[bh][n][32] bf16, vN[b][c][n] bf16.
// ---------------------------------------------------------------------------
__global__ __launch_bounds__(256) void gemm_kv(
    const short* __restrict__ Ak, const short* __restrict__ Av,
    const short* __restrict__ Bt,
    const float* __restrict__ bk, const float* __restrict__ bv,
    short* __restrict__ kT, short* __restrict__ vN)
{
    __shared__ short Ks[2][64 * 64];
    __shared__ short Vs[2][64 * 64];
    __shared__ short Bs[2][64 * 64];
    const int t = threadIdx.x;
    const int n0 = blockIdx.x * 64, m0 = blockIdx.y * 64;
    const int b = blockIdx.z;
    const int lane = t & 63, w = t >> 6;
    const int wm = w >> 1, wn = w & 1;
    const int l15 = lane & 15, g = lane >> 4;
    const int srow = t >> 3, sp = t & 7;
    f32x4 z = {0.f, 0.f, 0.f, 0.f};
    f32x4 acck[2][2], accv[2][2];
    acck[0][0] = z; acck[0][1] = z; acck[1][0] = z; acck[1][1] = z;
    accv[0][0] = z; accv[0][1] = z; accv[1][0] = z; accv[1][1] = z;

    bf16x8 a1[2], a2[2], bb[2];
    #pragma unroll
    for (int i = 0; i < 2; ++i) {
        int row = srow + i * 32;
        a1[i] = *(const bf16x8*)(Ak + (long)(m0 + row) * 256 + sp * 8);
        a2[i] = *(const bf16x8*)(Av + (long)(m0 + row) * 256 + sp * 8);
        bb[i] = *(const bf16x8*)(Bt + ((long)b * 1024 + n0 + row) * 256 + sp * 8);
        stpair(Ks[0], row, 64, sp, row & 15, a1[i]);
        stpair(Vs[0], row, 64, sp, row & 15, a2[i]);
        stpair(Bs[0], row, 64, sp, row & 15, bb[i]);
    }
    __syncthreads();

    for (int kt = 0; kt < 4; ++kt) {
        const int cur = kt & 1;
        if (kt < 3) {
            const int k0 = (kt + 1) * 64;
            #pragma unroll
            for (int i = 0; i < 2; ++i) {
                int row = srow + i * 32;
                a1[i] = *(const bf16x8*)(Ak + (long)(m0 + row) * 256 + k0 + sp * 8);
                a2[i] = *(const bf16x8*)(Av + (long)(m0 + row) * 256 + k0 + sp * 8);
                bb[i] = *(const bf16x8*)(Bt + ((long)b * 1024 + n0 + row) * 256 + k0 + sp * 8);
            }
        }
        #pragma unroll
        for (int kk = 0; kk < 2; ++kk) {
            bf16x8 afk[2], afv[2], bfr[2];
            #pragma unroll
            for (int mi = 0; mi < 2; ++mi) {
                int row = wm * 32 + mi * 16 + l15;
                afk[mi] = ldfrag(Ks[cur], row, 64, kk * 8 + g, kk * 8 + 4 + g, row & 15);
                afv[mi] = ldfrag(Vs[cur], row, 64, kk * 8 + g, kk * 8 + 4 + g, row & 15);
            }
            #pragma unroll
            for (int ni = 0; ni < 2; ++ni) {
                int row = wn * 32 + ni * 16 + l15;
                bfr[ni] = ldfrag(Bs[cur], row, 64, kk * 8 + g, kk * 8 + 4 + g, row & 15);
            }
            __builtin_amdgcn_s_setprio(1);
            #pragma unroll
            for (int mi = 0; mi < 2; ++mi)
                #pragma unroll
                for (int ni = 0; ni < 2; ++ni) {
                    acck[mi][ni] = __builtin_amdgcn_mfma_f32_16x16x32_bf16(
                        afk[mi], bfr[ni], acck[mi][ni], 0, 0, 0);
                    accv[mi][ni] = __builtin_amdgcn_mfma_f32_16x16x32_bf16(
                        afv[mi], bfr[ni], accv[mi][ni], 0, 0, 0);
                }
            __builtin_amdgcn_s_setprio(0);
        }
        if (kt < 3) {
            #pragma unroll
            for (int i = 0; i < 2; ++i) {
                int row = srow + i * 32;
                stpair(Ks[cur ^ 1], row, 64, sp, row & 15, a1[i]);
                stpair(Vs[cur ^ 1], row, 64, sp, row & 15, a2[i]);
                stpair(Bs[cur ^ 1], row, 64, sp, row & 15, bb[i]);
            }
        }
        __syncthreads();
    }
    #pragma unroll
    for (int mi = 0; mi < 2; ++mi) {
        const int mbase = m0 + wm * 32 + mi * 16 + g * 4;
        float bk4[4], bv4[4];
        #pragma unroll
        for (int j = 0; j < 4; ++j) { bk4[j] = bk[mbase + j]; bv4[j] = bv[mbase + j]; }
        #pragma unroll
        for (int ni = 0; ni < 2; ++ni) {
            const int n = n0 + wn * 32 + ni * 16 + l15;
            f32x4 rk = acck[mi][ni], rv = accv[mi][ni];
            short4v pk = {f2bf(rk[0] + bk4[0]), f2bf(rk[1] + bk4[1]),
                          f2bf(rk[2] + bk4[2]), f2bf(rk[3] + bk4[3])};
            int bh = b * 8 + (mbase >> 5);
            *(short4v*)(kT + ((long)bh * 1024 + n) * 32 + (mbase & 31)) = pk;
            #pragma unroll
            for (int j = 0; j < 4; ++j)
                vN[((long)b * 256 + mbase + j) * NPOS + n] = f2bf(rv[j] + bv4[j]);
        }
    }
}

// ---------------------------------------------------------------------------
// Offset branch, cooperative: one block per (bg, image row y).
// ---------------------------------------------------------------------------
__global__ __launch_bounds__(256) void offset_kernel(const float* __restrict__ q,
    const float* __restrict__ dww, const float* __restrict__ dwb,
    const float* __restrict__ lng, const float* __restrict__ lnb,
    const float* __restrict__ pww, float* __restrict__ pos)
{
    __shared__ float q3[64][3][33];   // [c][row][x]
    __shared__ float wS[576];
    __shared__ float bS[64], gS[64], lbS[64], pS[128];
    const int t = threadIdx.x;
    const int y = blockIdx.x, bg = blockIdx.y;
    const float* qb = q + (long)bg * 64 * NPOS;
    for (int i = t; i < 576; i += 256) wS[i] = dww[i];
    if (t < 64) { bS[t] = dwb[t]; gS[t] = lng[t]; lbS[t] = lnb[t]; }
    else if (t >= 128 && t < 256) pS[t - 128] = pww[t - 128];
    #pragma unroll
    for (int i = 0; i < 6; ++i) {
        int id = t + i * 256;                 // 0..1535 = 64c x 3r x 8 float4
        int c = id / 24, rx = id - c * 24;
        int r = rx >> 3, q4 = (rx & 7) * 4;
        int yy = y + r - 1;
        float4 v = make_float4(0.f, 0.f, 0.f, 0.f);
        if (yy >= 0 && yy < 32)
            v = *(const float4*)(qb + (long)c * NPOS + yy * 32 + q4);
        q3[c][r][q4 + 0] = v.x; q3[c][r][q4 + 1] = v.y;
        q3[c][r][q4 + 2] = v.z; q3[c][r][q4 + 3] = v.w;
    }
    __syncthreads();
    const int p = t >> 3, cg = t & 7;
    float oc[8];
    float s = 0.f, s2 = 0.f;
    #pragma unroll
    for (int j = 0; j < 8; ++j) {
        int c = cg * 8 + j;
        float acc = bS[c];
        #pragma unroll
        for (int dy = 0; dy < 3; ++dy)
            #pragma unroll
            for (int dx = 0; dx < 3; ++dx) {
                int xx = p + dx - 1;
                if (xx >= 0 && xx < 32)
                    acc += wS[c * 9 + dy * 3 + dx] * q3[c][dy][xx];
            }
        oc[j] = acc;
        s += acc; s2 += acc * acc;
    }
    s  += __shfl_xor(s, 1);  s  += __shfl_xor(s, 2);  s  += __shfl_xor(s, 4);
    s2 += __shfl_xor(s2, 1); s2 += __shfl_xor(s2, 2); s2 += __shfl_xor(s2, 4);
    float mu = s * 0.015625f;
    float var = s2 * 0.015625f - mu * mu;
    float rstd = rsqrtf(var + 1e-5f);
    float a0 = 0.f, a1 = 0.f;
    #pragma unroll
    for (int j = 0; j < 8; ++j) {
        int c = cg * 8 + j;
        float on = (oc[j] - mu) * rstd * gS[c] + lbS[c];
        float ge = 0.5f * on * (1.f + erff(on * 0.70710678118654752f));
        a0 += pS[c] * ge;
        a1 += pS[64 + c] * ge;
    }
    a0 += __shfl_xor(a0, 1); a0 += __shfl_xor(a0, 2); a0 += __shfl_xor(a0, 4);
    a1 += __shfl_xor(a1, 1); a1 += __shfl_xor(a1, 2); a1 += __shfl_xor(a1, 4);
    if (cg == 0) {
        const float rng = 4.f / 31.f;
        float offy = tanhf(a0) * rng;
        float offx = tanhf(a1) * rng;
        float ry = ((y + 0.5f) / 31.f) * 2.f - 1.f;
        float rx = ((p + 0.5f) / 31.f) * 2.f - 1.f;
        int pp = y * 32 + p;
        pos[(long)bg * 2048 + pp * 2 + 0] = offy + ry;
        pos[(long)bg * 2048 + pp * 2 + 1] = offx + rx;
    }
}

// ---------------------------------------------------------------------------
// Bilinear grid-sample -> bf16 xsT[b][p][c] (c fastest for coalesced writes).
// ---------------------------------------------------------------------------
__global__ void sample_kernel(const float* __restrict__ x,
    const float* __restrict__ pos, short* __restrict__ xsT)
{
    int gid = blockIdx.x * 256 + threadIdx.x;     // 2^21
    int cc = gid & 63;
    int p  = (gid >> 6) & 1023;
    int bg = gid >> 16;
    float py = pos[(long)bg * 2048 + p * 2 + 0];
    float px = pos[(long)bg * 2048 + p * 2 + 1];
    float fy = (py + 1.f) * 15.5f;
    float fx = (px + 1.f) * 15.5f;
    float y0f = floorf(fy), x0f = floorf(fx);
    int y0 = (int)y0f, x0 = (int)x0f;
    float yw = fy - y0f, xw = fx - x0f;
    const float* img = x + ((long)bg * 64 + cc) * NPOS;
    float acc = 0.f;
    { int yi = y0,     xi = x0;     float wg = (1.f - yw) * (1.f - xw);
      if (yi >= 0 && yi < 32 && xi >= 0 && xi < 32) acc += wg * img[yi * 32 + xi]; }
    { int yi = y0,     xi = x0 + 1; float wg = (1.f - yw) * xw;
      if (yi >= 0 && yi < 32 && xi >= 0 && xi < 32) acc += wg * img[yi * 32 + xi]; }
    { int yi = y0 + 1, xi = x0;     float wg = yw * (1.f - xw);
      if (yi >= 0 && yi < 32 && xi >= 0 && xi < 32) acc += wg * img[yi * 32 + xi]; }
    { int yi = y0 + 1, xi = x0 + 1; float wg = yw * xw;
      if (yi >= 0 && yi < 32 && xi >= 0 && xi < 32) acc += wg * img[yi * 32 + xi]; }
    xsT[((long)(bg >> 2) * 1024 + p) * 256 + (bg & 3) * 64 + cc] = f2bf(acc);
}

// ---------------------------------------------------------------------------
// MFMA flash attention (T12 swapped-operand), exp2 softmax (log2e pre-folded
// into qT), 2-phase double-buffered K/V (one barrier per tile), fused lepe.
// grid(16 mt, 64 bh), 4 waves.  LDS ~38.6KB -> 4 blocks/CU.
// ---------------------------------------------------------------------------
__global__ __launch_bounds__(256) void attn_mfma(
    const short* __restrict__ qT, const short* __restrict__ kT,
    const short* __restrict__ vN, const float* __restrict__ qf,
    const float* __restrict__ rdw, const float* __restrict__ rdb,
    short* __restrict__ aoutT)
{
    __shared__ short qS[64 * 32];          // 4096 B
    __shared__ short kS[2][64 * 32];       // 8192 B
    __shared__ short vS[2][32 * 64];       // 8192 B
    __shared__ float oT[64 * 33];          // 8448 B
    __shared__ short qr[4][32][33];        // 8448 B (bf16 q rows for lepe)
    __shared__ float wR[288], bR[32];      // 1280 B
    const int t = threadIdx.x;
    const int mt = blockIdx.x, bh = blockIdx.y;
    const int m0 = mt * 64;
    const int lane = t & 63, w = t >> 6;
    const int l15 = lane & 15, g = lane >> 4;
    const long base32 = (long)bh * 32768;          // bh*32*1024
    const int c0 = (bh & 7) * 32;                  // global channel base
    const int krow_ = t >> 2, kh = t & 3;          // K staging coords
    const int vc = t >> 3, vh = t & 7;             // V staging coords
    f32x4 z = {0.f, 0.f, 0.f, 0.f};

    // stage Q tile (64 x 32)
    {
        bf16x8 v8 = *(const bf16x8*)(qT + base32 + (long)(m0 + krow_) * 32 + kh * 8);
        stpair(qS, krow_, 32, kh, (krow_ >> 1) & 7, v8);
    }
    // stage q rows 2mt-1..2mt+2 (bf16, zero-padded) for lepe + rpe weights
    {
        const int y0 = (m0 >> 5) - 1;
        #pragma unroll
        for (int i = 0; i < 4; ++i) {
            int id = t + i * 256;              // r(2) cc(5) xq(3)
            int xq = id & 7, cc = (id >> 3) & 31, r = id >> 8;
            int yy = y0 + r;
            float4 v = make_float4(0.f, 0.f, 0.f, 0.f);
            if (yy >= 0 && yy < 32)
                v = *(const float4*)(qf + base32 + (long)cc * NPOS + yy * 32 + xq * 4);
            qr[r][cc][xq * 4 + 0] = f2bf(v.x); qr[r][cc][xq * 4 + 1] = f2bf(v.y);
            qr[r][cc][xq * 4 + 2] = f2bf(v.z); qr[r][cc][xq * 4 + 3] = f2bf(v.w);
        }
        if (t < 32) bR[t] = rdb[c0 + t];
        for (int i = t; i < 288; i += 256) wR[i] = rdw[c0 * 9 + i];
    }
    // stage K/V tile 0 into buffer 0
    bf16x8 kr = *(const bf16x8*)(kT + base32 + (long)krow_ * 32 + kh * 8);
    bf16x8 vr = *(const bf16x8*)(vN + base32 + (long)vc * NPOS + vh * 8);
    stpair(kS[0], krow_, 32, kh, (krow_ >> 1) & 7, kr);
    stpair(vS[0], vc, 64, vh, vc & 15, vr);
    __syncthreads();

    const int qrow = w * 16 + l15;
    const bf16x8 qb = ldfrag(qS, qrow, 32, g, 4 + g, (qrow >> 1) & 7);

    float Mr = -1e30f, Lr = 0.f;
    f32x4 po[2]; po[0] = z; po[1] = z;

    for (int nt = 0; nt < 16; ++nt) {
        const int cur = nt & 1;
        if (nt < 15) {   // prefetch next tile into regs (hidden under compute)
            const int n0n = (nt + 1) * 64;
            kr = *(const bf16x8*)(kT + base32 + (long)(n0n + krow_) * 32 + kh * 8);
            vr = *(const bf16x8*)(vN + base32 + (long)vc * NPOS + n0n + vh * 8);
        }
        // S^T: 4 frags (16n each), K=32 in one mfma
        f32x4 s[4];
        __builtin_amdgcn_s_setprio(1);
        #pragma unroll
        for (int j = 0; j < 4; ++j) {
            int krow = j * 16 + l15;
            bf16x8 ka = ldfrag(kS[cur], krow, 32, g, 4 + g, (krow >> 1) & 7);
            s[j] = __builtin_amdgcn_mfma_f32_16x16x32_bf16(ka, qb, z, 0, 0, 0);
        }
        __builtin_amdgcn_s_setprio(0);
        // online softmax (base-2; log2e folded into q scale)
        float mx = -1e30f;
        #pragma unroll
        for (int j = 0; j < 4; ++j)
            #pragma unroll
            for (int r = 0; r < 4; ++r) mx = fmaxf(mx, s[j][r]);
        mx = fmaxf(mx, __shfl_xor(mx, 16));
        mx = fmaxf(mx, __shfl_xor(mx, 32));
        float Mn = fmaxf(Mr, mx);
        float esc = exp2f(Mr - Mn);
        Mr = Mn;
        float ls = 0.f;
        #pragma unroll
        for (int j = 0; j < 4; ++j)
            #pragma unroll
            for (int r = 0; r < 4; ++r) { s[j][r] = exp2f(s[j][r] - Mn); ls += s[j][r]; }
        ls += __shfl_xor(ls, 16);
        ls += __shfl_xor(ls, 32);
        Lr = Lr * esc + ls;
        po[0] *= esc; po[1] *= esc;
        // P^T B-frags straight from S^T registers (v_cvt_pk_bf16_f32)
        bf16x8 pb[2];
        #pragma unroll
        for (int ks = 0; ks < 2; ++ks) {
            uint4v u;
            u[0] = cvtpk(s[2 * ks][0], s[2 * ks][1]);
            u[1] = cvtpk(s[2 * ks][2], s[2 * ks][3]);
            u[2] = cvtpk(s[2 * ks + 1][0], s[2 * ks + 1][1]);
            u[3] = cvtpk(s[2 * ks + 1][2], s[2 * ks + 1][3]);
            pb[ks] = __builtin_bit_cast(bf16x8, u);
        }
        // PV: O^T[c][m] += V[c][n] * P^T[n][m]
        __builtin_amdgcn_s_setprio(1);
        #pragma unroll
        for (int cs = 0; cs < 2; ++cs) {
            int vrow = cs * 16 + l15;
            #pragma unroll
            for (int ks = 0; ks < 2; ++ks) {
                bf16x8 va = ldfrag(vS[cur], vrow, 64, ks * 8 + g, ks * 8 + 4 + g, vrow & 15);
                po[cs] = __builtin_amdgcn_mfma_f32_16x16x32_bf16(va, pb[ks], po[cs], 0, 0, 0);
            }
        }
        __builtin_amdgcn_s_setprio(0);
        if (nt < 15) {   // write prefetched tile into the other buffer
            stpair(kS[cur ^ 1], krow_, 32, kh, (krow_ >> 1) & 7, kr);
            stpair(vS[cur ^ 1], vc, 64, vh, vc & 15, vr);
        }
        __syncthreads();
    }
    // epilogue: oT[m][c], then + lepe conv from qr, write bf16 aoutT[b][p][c]
    float inv = 1.f / Lr;
    #pragma unroll
    for (int cs = 0; cs < 2; ++cs)
        #pragma unroll
        for (int r = 0; r < 4; ++r)
            oT[(w * 16 + l15) * 33 + cs * 16 + g * 4 + r] = po[cs][r] * inv;
    __syncthreads();
    #pragma unroll
    for (int i = 0; i < 8; ++i) {
        int idx = t + i * 256;
        int c = idx & 31, m = idx >> 5;
        int ml = m >> 5, xx0 = m & 31;        // local row, x
        float acc = 0.f;
        #pragma unroll
        for (int dy = 0; dy < 3; ++dy)
            #pragma unroll
            for (int dx = 0; dx < 3; ++dx) {
                int xx = xx0 + dx - 1;
                if (xx >= 0 && xx < 32)
                    acc += wR[c * 9 + dy * 3 + dx] * bf2f(qr[ml + dy][c][xx]);
            }
        float v = oT[m * 33 + c] + acc + bR[c];
        aoutT[(((long)(bh >> 3)) * 1024 + m0 + m) * 256 + (bh & 7) * 32 + c] = f2bf(v);
    }
}

// ---------------------------------------------------------------------------
extern "C" void kernel_launch(void* const* d_in, const int* in_sizes, int n_in,
                              void* d_out, int out_size, void* d_ws, size_t ws_size,
                              hipStream_t stream)
{
    const float* x   = (const float*)d_in[0];
    const float* Wq  = (const float*)d_in[1];
    const float* bq  = (const float*)d_in[2];
    const float* Wk  = (const float*)d_in[3];
    const float* bk  = (const float*)d_in[4];
    const float* Wv  = (const float*)d_in[5];
    const float* bv  = (const float*)d_in[6];
    const float* Wo  = (const float*)d_in[7];
    const float* bo  = (const float*)d_in[8];
    const float* odw = (const float*)d_in[9];
    const float* odb = (const float*)d_in[10];
    const float* olg = (const float*)d_in[11];
    const float* olb = (const float*)d_in[12];
    const float* opw = (const float*)d_in[13];
    const float* rdw = (const float*)d_in[14];
    const float* rdb = (const float*)d_in[15];

    float* ws = (float*)d_ws;
    const size_t SZ = (size_t)2097152;            // 2M elements per big buffer
    float* qf  = ws;                              // fp32 q  [8][256][1024]
    float* pos = ws + SZ;                         // 65536 floats
    short* sb  = (short*)(ws + SZ + 65536);       // bf16 region (16B aligned)
    short* Wb  = sb;                              // 4 x 65536
    short* xT  = Wb + 262144;                     // [8][1024][256]
    short* xsT = xT + SZ;                         // [8][1024][256]
    short* qTb = xsT + SZ;                        // [64][1024][32]
    short* kTb = qTb + SZ;                        // [64][1024][32]
    short* vNb = kTb + SZ;                        // [8][256][1024]
    short* aoT = xT;                              // alias: xT dead after q GEMM
    float* y   = (float*)d_out;

    dim3 gg(16, 4, 8);
    cvt_w<<<1024, 256, 0, stream>>>(Wq, Wk, Wv, Wo, Wb);
    transpose_x<<<gg, 256, 0, stream>>>(x, xT);
    gemm_mfma<0><<<gg, 256, 0, stream>>>(Wb, xT, bq, qf, qTb);
    offset_kernel<<<dim3(32, 32), 256, 0, stream>>>(qf, odw, odb, olg, olb, opw, pos);
    sample_kernel<<<8192, 256, 0, stream>>>(x, pos, xsT);
    gemm_kv<<<gg, 256, 0, stream>>>(Wb + 65536, Wb + 131072, xsT, bk, bv, kTb, vNb);
    attn_mfma<<<dim3(16, 64), 256, 0, stream>>>(qTb, kTb, vNb, qf, rdw, rdb, aoT);
    gemm_mfma<3><<<gg, 256, 0, stream>>>(Wb + 196608, aoT, bo, y, nullptr);
}